// Round 3
// baseline (550.190 us; speedup 1.0000x reference)
//
#include <hip/hip_runtime.h>

typedef _Float16 f16;
typedef _Float16 f16x8 __attribute__((ext_vector_type(8)));
typedef _Float16 f16x4 __attribute__((ext_vector_type(4)));
typedef float f32x4 __attribute__((ext_vector_type(4)));

#define MFMA16(A, B, C) __builtin_amdgcn_mfma_f32_16x16x32_f16((A), (B), (C), 0, 0, 0)

// async global->LDS, 16B per lane, dest = wave-uniform base + lane*16
__device__ __forceinline__ void async16(void* lds, const void* gp) {
    __builtin_amdgcn_global_load_lds(
        (__attribute__((address_space(1))) void*)(gp),
        (__attribute__((address_space(3))) void*)(lds), 16, 0, 0);
}

// ---------------- fp32 -> fp16 cast (vectorized) ----------------
__global__ __launch_bounds__(256) void k_convert(const float* __restrict__ in,
                                                 f16* __restrict__ out, int n) {
    int i = (blockIdx.x * 256 + threadIdx.x) * 4;
    if (i + 3 < n) {
        float4 v = *(const float4*)(in + i);
        f16x4 o = {(f16)v.x, (f16)v.y, (f16)v.z, (f16)v.w};
        *(f16x4*)(out + i) = o;
    }
}

// ---------------- transpose + cast all four 1024x1024 weights in one launch ----------------
__global__ __launch_bounds__(256) void k_transpose_w4(const float* __restrict__ Wq,
                                                      const float* __restrict__ Wk,
                                                      const float* __restrict__ Wv,
                                                      const float* __restrict__ Wr,
                                                      f16* __restrict__ Wqkvt,
                                                      f16* __restrict__ Wrt) {
    __shared__ float tile[32][33];
    int z = blockIdx.z;
    const float* W = (z == 0) ? Wq : (z == 1) ? Wk : (z == 2) ? Wv : Wr;
    f16* Wt = (z == 3) ? Wrt : Wqkvt + z * 1048576;
    int c0 = blockIdx.x * 32, r0 = blockIdx.y * 32;
    int tx = threadIdx.x, ty = threadIdx.y;  // 32 x 8
#pragma unroll
    for (int j = 0; j < 32; j += 8)
        tile[ty + j][tx] = W[(r0 + ty + j) * 1024 + c0 + tx];
    __syncthreads();
#pragma unroll
    for (int j = 0; j < 32; j += 8)
        Wt[(c0 + ty + j) * 1024 + r0 + tx] = (f16)tile[tx][ty + j];
}

// ---------------- transpose V slice of QKV into Vt[bh][d][s] ----------------
__global__ __launch_bounds__(256) void k_transpose_v(const f16* __restrict__ QKV,
                                                     f16* __restrict__ Vt) {
    __shared__ f16 tile[32][33];
    int s0 = blockIdx.x * 32;
    int d0 = blockIdx.y * 32;
    int bh = blockIdx.z;
    int b = bh >> 4, h = bh & 15;
    int tx = threadIdx.x, ty = threadIdx.y;  // 32 x 8
#pragma unroll
    for (int j = 0; j < 32; j += 8)
        tile[ty + j][tx] = QKV[(b * 2048 + s0 + ty + j) * 3072 + 2048 + h * 64 + d0 + tx];
    __syncthreads();
#pragma unroll
    for (int j = 0; j < 32; j += 8)
        Vt[(bh * 64 + d0 + ty + j) * 2048 + s0 + tx] = tile[tx][ty + j];
}

// ---------------- GEMM: C[M][N] = A[M][K] * Bt[N][K]^T, async-LDS staging ----------------
// 128x128 tile, BK=32, 256 threads. Unpadded LDS; 16B chunk c of row r stored at slot
// c ^ ((r>>1)&3): async writes are lane-contiguous, frag reads per-beat conflict-free.
template <bool OUT_F16>
__global__ __launch_bounds__(256) void k_gemm_bt(const f16* __restrict__ A,
                                                 const f16* __restrict__ Bt,
                                                 void* __restrict__ Cv,
                                                 int M, int N, int K) {
    __shared__ f16 As[128][32];
    __shared__ f16 Bs[128][32];
    int t = threadIdx.x;
    int lane = t & 63, w = t >> 6;
    int wm = (w >> 1) * 64, wn = (w & 1) * 64;
    int m0 = blockIdx.y * 128, n0 = blockIdx.x * 128;
    int ln = lane & 15, g = lane >> 4;

    // async staging map: two 64-chunk instructions per matrix per wave
    int lin0 = w * 128 + lane, lin1 = lin0 + 64;
    int r0 = lin0 >> 2, c0 = (lin0 & 3) ^ ((r0 >> 1) & 3);
    int r1 = lin1 >> 2, c1 = (lin1 & 3) ^ ((r1 >> 1) & 3);
    const f16* gA0 = A + (size_t)(m0 + r0) * K + c0 * 8;
    const f16* gA1 = A + (size_t)(m0 + r1) * K + c1 * 8;
    const f16* gB0 = Bt + (size_t)(n0 + r0) * K + c0 * 8;
    const f16* gB1 = Bt + (size_t)(n0 + r1) * K + c1 * 8;
    f16* lA0 = &As[0][0] + w * 1024;
    f16* lB0 = &Bs[0][0] + w * 1024;

    f32x4 acc[4][4] = {};
    int sw = (ln >> 1) & 3;

    for (int k0 = 0; k0 < K; k0 += 32) {
        __syncthreads();
        async16(lA0, gA0 + k0);
        async16(lA0 + 512, gA1 + k0);
        async16(lB0, gB0 + k0);
        async16(lB0 + 512, gB1 + k0);
        __syncthreads();
        f16x8 af[4], bf[4];
#pragma unroll
        for (int i = 0; i < 4; i++) {
            af[i] = *(const f16x8*)&As[wm + i * 16 + ln][(g ^ sw) * 8];
            bf[i] = *(const f16x8*)&Bs[wn + i * 16 + ln][(g ^ sw) * 8];
        }
#pragma unroll
        for (int mt = 0; mt < 4; mt++)
#pragma unroll
            for (int nt = 0; nt < 4; nt++)
                acc[mt][nt] = MFMA16(af[mt], bf[nt], acc[mt][nt]);
    }

    int rg = g * 4;
#pragma unroll
    for (int mt = 0; mt < 4; mt++)
#pragma unroll
        for (int nt = 0; nt < 4; nt++)
#pragma unroll
            for (int r = 0; r < 4; r++) {
                int row = m0 + wm + mt * 16 + rg + r;
                int col = n0 + wn + nt * 16 + ln;
                float v = acc[mt][nt][r];
                if (OUT_F16)
                    ((f16*)Cv)[(size_t)row * N + col] = (f16)v;
                else
                    ((float*)Cv)[(size_t)row * N + col] = v;
            }
}

// ---------------- flash attention v6: in-register P, one q-tile per block ----------------
// QK^T computes S^T (D[m=k][n=q]). Physical LDS row P holds global K-row rho^-1(P),
// achieved by permuting the GLOBAL row each staging thread loads (LDS writes stay in
// v3's natural, low-conflict order; global coalescing unchanged -- rows are 6KB apart
// either way). The S^T C-layout then lands with k = kb*32 + 8g + 4*hi + r, exactly the
// PV A-fragment order: exp2 results pack straight into the PV A operand. NO LDS for P,
// no cross-lane ops. Double-buffered K/V -> one barrier per tile; staging writes +
// global prefetch overlap compute. Grid = 1024 one-q-tile blocks -> 4 blocks/CU.
__global__ __launch_bounds__(256, 4) void k_attn(const f16* __restrict__ QKV,
                                                 const f16* __restrict__ Vt,
                                                 f16* __restrict__ Ob) {
    __shared__ f16 Ks[2][64][72];
    __shared__ f16 Vs[2][64][72];  // V^T tile: [d][k]
    int qt = blockIdx.x, bh = blockIdx.y;
    int b = bh >> 4, h = bh & 15;
    int t = threadIdx.x, lane = t & 63, wq = t >> 6;
    int ln = lane & 15, g = lane >> 4, g8 = g * 8, rg = g * 4;

    // staging coords: two K chunks + two V chunks per thread per tile
    int kr0 = t >> 3, kc0 = (t & 7) * 8;   // physical rows 0..31 (natural write order)
    int kr1 = kr0 + 32;                    // physical rows 32..63
    // global K-row to load = rho^-1(physical row); bit5 preserved
    int kg0 = ((kr0 & 16) >> 2) | ((kr0 & 12) << 1) | (kr0 & 3);
    int kg1 = kg0 + 32;
    const f16* Kbase = QKV + (size_t)b * 2048 * 3072 + 1024 + h * 64;
    const f16* Vbase = Vt + (size_t)bh * 64 * 2048;

    const float C_SCL = 0.18033688f;   // 0.125 * log2(e)
    const float C_MSK = -72.134752f;   // -50 * log2(e)
    f16x8 ones;
#pragma unroll
    for (int j = 0; j < 8; j++) ones[j] = (f16)1.f;

    int q0 = qt * 128;
    int nk = 2 * qt + 2;  // causal: k-tiles 0..2qt+1

    int4 rk0, rk1, rv0, rv1;
#define LOADT(j)                                                          \
    do {                                                                  \
        size_t kO = (size_t)(j) * 64;                                     \
        rk0 = *(const int4*)(Kbase + (kO + kg0) * 3072 + kc0);            \
        rk1 = *(const int4*)(Kbase + (kO + kg1) * 3072 + kc0);            \
        rv0 = *(const int4*)(Vbase + (size_t)kr0 * 2048 + kO + kc0);      \
        rv1 = *(const int4*)(Vbase + (size_t)kr1 * 2048 + kO + kc0);      \
    } while (0)
#define STORET(bi)                                                        \
    do {                                                                  \
        *(int4*)&Ks[bi][kr0][kc0] = rk0;                                  \
        *(int4*)&Ks[bi][kr1][kc0] = rk1;                                  \
        *(int4*)&Vs[bi][kr0][kc0] = rv0;                                  \
        *(int4*)&Vs[bi][kr1][kc0] = rv1;                                  \
    } while (0)

    LOADT(0);
    STORET(0);
    LOADT(1);
    __syncthreads();

    f16x8 bq[2][2];
#pragma unroll
    for (int nt = 0; nt < 2; nt++)
#pragma unroll
        for (int kd = 0; kd < 2; kd++)
            bq[nt][kd] = *(const f16x8*)(QKV +
                (size_t)(b * 2048 + q0 + wq * 32 + nt * 16 + ln) * 3072 +
                h * 64 + kd * 32 + g8);

    f32x4 oacc[2][4] = {};
    f32x4 osum[2] = {};

    for (int kt = 0; kt < nk; kt++) {
        int cur = kt & 1;
        int k0 = kt * 64;
        // tile fully above this wave's diagonal -> contributes ~e^-50 ~ 0
        bool active = (k0 <= q0 + wq * 32 + 31);  // wave-uniform

        f16x8 ak[2][4];
        if (active) {
#pragma unroll
            for (int kd = 0; kd < 2; kd++)
#pragma unroll
                for (int mt = 0; mt < 4; mt++)
                    ak[kd][mt] = *(const f16x8*)&Ks[cur][mt * 16 + ln][kd * 32 + g8];
        }
        // stage next tile into other buffer (safe: all waves finished reading it
        // before last barrier), then prefetch the tile after that from global.
        if (kt + 1 < nk) STORET(cur ^ 1);
        if (kt + 2 < nk) LOADT(kt + 2);

        if (active) {
            // S^T tile: D[m=physical k-row][n=q]; physical row P holds k = rho^-1(P)
            f32x4 sacc[4][2] = {};
#pragma unroll
            for (int kd = 0; kd < 2; kd++)
#pragma unroll
                for (int mt = 0; mt < 4; mt++)
#pragma unroll
                    for (int nt = 0; nt < 2; nt++)
                        sacc[mt][nt] = MFMA16(ak[kd][mt], bq[nt][kd], sacc[mt][nt]);

            // softmax numerator (fixed max 0), packed directly into PV A-fragments.
            // sacc[mt][nt][r] = S[k = k0 + (mt>>1)*32 + 8g + 4*(mt&1) + r][q = nt*16+ln]
            bool needs_mask = (k0 + 63 > q0 + wq * 32);
            f16x8 ap[2][2];
#pragma unroll
            for (int nt = 0; nt < 2; nt++) {
                int q = q0 + wq * 32 + nt * 16 + ln;
#pragma unroll
                for (int mt = 0; mt < 4; mt++) {
                    int kb = mt >> 1, hi4 = (mt & 1) * 4;
#pragma unroll
                    for (int r = 0; r < 4; r++) {
                        float e;
                        if (needs_mask) {
                            int kk = k0 + kb * 32 + hi4 + 8 * g + r;
                            e = __builtin_amdgcn_exp2f(
                                fmaf(sacc[mt][nt][r], C_SCL, (kk > q) ? C_MSK : 0.f));
                        } else {
                            e = __builtin_amdgcn_exp2f(sacc[mt][nt][r] * C_SCL);
                        }
                        ap[nt][kb][hi4 + r] = (f16)e;
                    }
                }
            }

            // O += P.V ; rowsum += P.1  (P entirely in registers)
#pragma unroll
            for (int kk = 0; kk < 2; kk++) {
                f16x8 bv[4];
#pragma unroll
                for (int dt = 0; dt < 4; dt++)
                    bv[dt] = *(const f16x8*)&Vs[cur][dt * 16 + ln][kk * 32 + g8];
#pragma unroll
                for (int nt = 0; nt < 2; nt++) {
#pragma unroll
                    for (int dt = 0; dt < 4; dt++)
                        oacc[nt][dt] = MFMA16(ap[nt][kk], bv[dt], oacc[nt][dt]);
                    osum[nt] = MFMA16(ap[nt][kk], ones, osum[nt]);
                }
            }
        }
        __syncthreads();  // buf[cur^1] staged; all waves done reading buf[cur]
    }

    // epilogue: osum C-layout row = 4g+r matches oacc rows exactly
#pragma unroll
    for (int nt = 0; nt < 2; nt++)
#pragma unroll
        for (int r = 0; r < 4; r++) {
            float inv = __builtin_amdgcn_rcpf(osum[nt][r]);
            int row = b * 2048 + q0 + wq * 32 + nt * 16 + rg + r;
#pragma unroll
            for (int dt = 0; dt < 4; dt++)
                Ob[(size_t)row * 1024 + h * 64 + dt * 16 + ln] =
                    (f16)(oacc[nt][dt][r] * inv);
        }
#undef LOADT
#undef STORET
}

// ---------------- host launch ----------------
extern "C" void kernel_launch(void* const* d_in, const int* in_sizes, int n_in,
                              void* d_out, int out_size, void* d_ws, size_t ws_size,
                              hipStream_t stream) {
    const float* x = (const float*)d_in[0];
    const float* Wq = (const float*)d_in[1];
    const float* Wk = (const float*)d_in[2];
    const float* Wv = (const float*)d_in[3];
    const float* Wr = (const float*)d_in[4];
    float* out = (float*)d_out;

    f16* ws = (f16*)d_ws;
    f16* xb    = ws;                    // 8192*1024
    f16* Wqkvt = xb + 8388608;          // 3072*1024
    f16* Wrt   = Wqkvt + 3145728;       // 1024*1024
    f16* QKVb  = Wrt + 1048576;         // 8192*3072
    f16* Vtb   = QKVb + 25165824;       // 64bh * 64d * 2048s
    f16* Obuf  = Vtb + 8388608;         // 8192*1024

    k_convert<<<8192, 256, 0, stream>>>(x, xb, 8388608);
    dim3 tb(32, 8);
    k_transpose_w4<<<dim3(32, 32, 4), tb, 0, stream>>>(Wq, Wk, Wv, Wr, Wqkvt, Wrt);
    k_gemm_bt<true><<<dim3(24, 64), 256, 0, stream>>>(xb, Wqkvt, QKVb, 8192, 3072, 1024);
    k_transpose_v<<<dim3(64, 2, 64), tb, 0, stream>>>(QKVb, Vtb);
    k_attn<<<dim3(16, 64), 256, 0, stream>>>(QKVb, Vtb, Obuf);
    k_gemm_bt<false><<<dim3(8, 64), 256, 0, stream>>>(Obuf, Wrt, out, 8192, 1024, 1024);
}

// Round 4
// 297.197 us; speedup vs baseline: 1.8513x; 1.8513x over previous
//
#include <hip/hip_runtime.h>

typedef _Float16 f16;
typedef _Float16 f16x8 __attribute__((ext_vector_type(8)));
typedef _Float16 f16x4 __attribute__((ext_vector_type(4)));
typedef float f32x4 __attribute__((ext_vector_type(4)));

#define MFMA16(A, B, C) __builtin_amdgcn_mfma_f32_16x16x32_f16((A), (B), (C), 0, 0, 0)

// async global->LDS, 16B per lane, dest = wave-uniform base + lane*16
__device__ __forceinline__ void async16(void* lds, const void* gp) {
    __builtin_amdgcn_global_load_lds(
        (__attribute__((address_space(1))) void*)(gp),
        (__attribute__((address_space(3))) void*)(lds), 16, 0, 0);
}

// ---------------- fp32 -> fp16 cast (vectorized) ----------------
__global__ __launch_bounds__(256) void k_convert(const float* __restrict__ in,
                                                 f16* __restrict__ out, int n) {
    int i = (blockIdx.x * 256 + threadIdx.x) * 4;
    if (i + 3 < n) {
        float4 v = *(const float4*)(in + i);
        f16x4 o = {(f16)v.x, (f16)v.y, (f16)v.z, (f16)v.w};
        *(f16x4*)(out + i) = o;
    }
}

// ---------------- transpose + cast all four 1024x1024 weights in one launch ----------------
__global__ __launch_bounds__(256) void k_transpose_w4(const float* __restrict__ Wq,
                                                      const float* __restrict__ Wk,
                                                      const float* __restrict__ Wv,
                                                      const float* __restrict__ Wr,
                                                      f16* __restrict__ Wqkvt,
                                                      f16* __restrict__ Wrt) {
    __shared__ float tile[32][33];
    int z = blockIdx.z;
    const float* W = (z == 0) ? Wq : (z == 1) ? Wk : (z == 2) ? Wv : Wr;
    f16* Wt = (z == 3) ? Wrt : Wqkvt + z * 1048576;
    int c0 = blockIdx.x * 32, r0 = blockIdx.y * 32;
    int tx = threadIdx.x, ty = threadIdx.y;  // 32 x 8
#pragma unroll
    for (int j = 0; j < 32; j += 8)
        tile[ty + j][tx] = W[(r0 + ty + j) * 1024 + c0 + tx];
    __syncthreads();
#pragma unroll
    for (int j = 0; j < 32; j += 8)
        Wt[(c0 + ty + j) * 1024 + r0 + tx] = (f16)tile[tx][ty + j];
}

// ---------------- transpose V slice of QKV into Vt[bh][d][s] ----------------
__global__ __launch_bounds__(256) void k_transpose_v(const f16* __restrict__ QKV,
                                                     f16* __restrict__ Vt) {
    __shared__ f16 tile[32][33];
    int s0 = blockIdx.x * 32;
    int d0 = blockIdx.y * 32;
    int bh = blockIdx.z;
    int b = bh >> 4, h = bh & 15;
    int tx = threadIdx.x, ty = threadIdx.y;  // 32 x 8
#pragma unroll
    for (int j = 0; j < 32; j += 8)
        tile[ty + j][tx] = QKV[(b * 2048 + s0 + ty + j) * 3072 + 2048 + h * 64 + d0 + tx];
    __syncthreads();
#pragma unroll
    for (int j = 0; j < 32; j += 8)
        Vt[(bh * 64 + d0 + ty + j) * 2048 + s0 + tx] = tile[tx][ty + j];
}

// ---------------- GEMM: C[M][N] = A[M][K] * Bt[N][K]^T, async-LDS staging ----------------
// 128x128 tile, BK=32, 256 threads. Unpadded LDS; 16B chunk c of row r stored at slot
// c ^ ((r>>1)&3): async writes are lane-contiguous, frag reads per-beat conflict-free.
template <bool OUT_F16>
__global__ __launch_bounds__(256) void k_gemm_bt(const f16* __restrict__ A,
                                                 const f16* __restrict__ Bt,
                                                 void* __restrict__ Cv,
                                                 int M, int N, int K) {
    __shared__ f16 As[128][32];
    __shared__ f16 Bs[128][32];
    int t = threadIdx.x;
    int lane = t & 63, w = t >> 6;
    int wm = (w >> 1) * 64, wn = (w & 1) * 64;
    int m0 = blockIdx.y * 128, n0 = blockIdx.x * 128;
    int ln = lane & 15, g = lane >> 4;

    // async staging map: two 64-chunk instructions per matrix per wave
    int lin0 = w * 128 + lane, lin1 = lin0 + 64;
    int r0 = lin0 >> 2, c0 = (lin0 & 3) ^ ((r0 >> 1) & 3);
    int r1 = lin1 >> 2, c1 = (lin1 & 3) ^ ((r1 >> 1) & 3);
    const f16* gA0 = A + (size_t)(m0 + r0) * K + c0 * 8;
    const f16* gA1 = A + (size_t)(m0 + r1) * K + c1 * 8;
    const f16* gB0 = Bt + (size_t)(n0 + r0) * K + c0 * 8;
    const f16* gB1 = Bt + (size_t)(n0 + r1) * K + c1 * 8;
    f16* lA0 = &As[0][0] + w * 1024;
    f16* lB0 = &Bs[0][0] + w * 1024;

    f32x4 acc[4][4] = {};
    int sw = (ln >> 1) & 3;

    for (int k0 = 0; k0 < K; k0 += 32) {
        __syncthreads();
        async16(lA0, gA0 + k0);
        async16(lA0 + 512, gA1 + k0);
        async16(lB0, gB0 + k0);
        async16(lB0 + 512, gB1 + k0);
        __syncthreads();
        f16x8 af[4], bf[4];
#pragma unroll
        for (int i = 0; i < 4; i++) {
            af[i] = *(const f16x8*)&As[wm + i * 16 + ln][(g ^ sw) * 8];
            bf[i] = *(const f16x8*)&Bs[wn + i * 16 + ln][(g ^ sw) * 8];
        }
#pragma unroll
        for (int mt = 0; mt < 4; mt++)
#pragma unroll
            for (int nt = 0; nt < 4; nt++)
                acc[mt][nt] = MFMA16(af[mt], bf[nt], acc[mt][nt]);
    }

    int rg = g * 4;
#pragma unroll
    for (int mt = 0; mt < 4; mt++)
#pragma unroll
        for (int nt = 0; nt < 4; nt++)
#pragma unroll
            for (int r = 0; r < 4; r++) {
                int row = m0 + wm + mt * 16 + rg + r;
                int col = n0 + wn + nt * 16 + ln;
                float v = acc[mt][nt][r];
                if (OUT_F16)
                    ((f16*)Cv)[(size_t)row * N + col] = (f16)v;
                else
                    ((float*)Cv)[(size_t)row * N + col] = v;
            }
}

// ---------------- flash attention v7: in-register P, one q-tile per block --------------
// Same verified structure as v6 (round 3, passed): QK^T computes S^T; physical LDS row P
// holds global K-row rho^-1(P) via global-side row permutation at staging (LDS writes in
// natural low-conflict order); S^T C-layout lands k = kb*32 + 8g + 4*hi + r = exactly the
// PV A-fragment order -> P never touches LDS. Double-buffered K/V, one barrier per tile.
// Round-3 lesson: __launch_bounds__(256,4) forced the 64-VGPR class -> ~620 MB scratch
// spill (WRITE_SIZE counter), 2.2x slowdown. Reverted to (256,2): compiler takes ~100
// VGPR spill-free; hardware still gives 4 blocks/CU (100 VGPR -> 128-class = 4 w/SIMD;
// LDS 4x36.9KB = 147KB < 160KB). Grid transposed to (bh, qt) so same-qt blocks land 64
// apart in dispatch order -> balanced per-CU causal workload mix (heuristic only).
__global__ __launch_bounds__(256, 2) void k_attn(const f16* __restrict__ QKV,
                                                 const f16* __restrict__ Vt,
                                                 f16* __restrict__ Ob) {
    __shared__ f16 Ks[2][64][72];
    __shared__ f16 Vs[2][64][72];  // V^T tile: [d][k]
    int bh = blockIdx.x, qt = blockIdx.y;
    int b = bh >> 4, h = bh & 15;
    int t = threadIdx.x, lane = t & 63, wq = t >> 6;
    int ln = lane & 15, g = lane >> 4, g8 = g * 8, rg = g * 4;

    // staging coords: two K chunks + two V chunks per thread per tile
    int kr0 = t >> 3, kc0 = (t & 7) * 8;   // physical rows 0..31 (natural write order)
    int kr1 = kr0 + 32;                    // physical rows 32..63
    // global K-row to load = rho^-1(physical row); bit5 preserved
    int kg0 = ((kr0 & 16) >> 2) | ((kr0 & 12) << 1) | (kr0 & 3);
    int kg1 = kg0 + 32;
    const f16* Kbase = QKV + (size_t)b * 2048 * 3072 + 1024 + h * 64;
    const f16* Vbase = Vt + (size_t)bh * 64 * 2048;

    const float C_SCL = 0.18033688f;   // 0.125 * log2(e)
    const float C_MSK = -72.134752f;   // -50 * log2(e)
    f16x8 ones;
#pragma unroll
    for (int j = 0; j < 8; j++) ones[j] = (f16)1.f;

    int q0 = qt * 128;
    int nk = 2 * qt + 2;  // causal: k-tiles 0..2qt+1

    int4 rk0, rk1, rv0, rv1;
#define LOADT(j)                                                          \
    do {                                                                  \
        size_t kO = (size_t)(j) * 64;                                     \
        rk0 = *(const int4*)(Kbase + (kO + kg0) * 3072 + kc0);            \
        rk1 = *(const int4*)(Kbase + (kO + kg1) * 3072 + kc0);            \
        rv0 = *(const int4*)(Vbase + (size_t)kr0 * 2048 + kO + kc0);      \
        rv1 = *(const int4*)(Vbase + (size_t)kr1 * 2048 + kO + kc0);      \
    } while (0)
#define STORET(bi)                                                        \
    do {                                                                  \
        *(int4*)&Ks[bi][kr0][kc0] = rk0;                                  \
        *(int4*)&Ks[bi][kr1][kc0] = rk1;                                  \
        *(int4*)&Vs[bi][kr0][kc0] = rv0;                                  \
        *(int4*)&Vs[bi][kr1][kc0] = rv1;                                  \
    } while (0)

    LOADT(0);
    STORET(0);
    LOADT(1);
    __syncthreads();

    f16x8 bq[2][2];
#pragma unroll
    for (int nt = 0; nt < 2; nt++)
#pragma unroll
        for (int kd = 0; kd < 2; kd++)
            bq[nt][kd] = *(const f16x8*)(QKV +
                (size_t)(b * 2048 + q0 + wq * 32 + nt * 16 + ln) * 3072 +
                h * 64 + kd * 32 + g8);

    f32x4 oacc[2][4] = {};
    f32x4 osum[2] = {};

    for (int kt = 0; kt < nk; kt++) {
        int cur = kt & 1;
        int k0 = kt * 64;
        // tile fully above this wave's diagonal -> contributes ~e^-50 ~ 0
        bool active = (k0 <= q0 + wq * 32 + 31);  // wave-uniform

        f16x8 ak[2][4];
        if (active) {
#pragma unroll
            for (int kd = 0; kd < 2; kd++)
#pragma unroll
                for (int mt = 0; mt < 4; mt++)
                    ak[kd][mt] = *(const f16x8*)&Ks[cur][mt * 16 + ln][kd * 32 + g8];
        }
        // stage next tile into other buffer (safe: all waves finished reading it
        // before last barrier), then prefetch the tile after that from global.
        if (kt + 1 < nk) STORET(cur ^ 1);
        if (kt + 2 < nk) LOADT(kt + 2);

        if (active) {
            // S^T tile: D[m=physical k-row][n=q]; physical row P holds k = rho^-1(P)
            f32x4 sacc[4][2] = {};
#pragma unroll
            for (int kd = 0; kd < 2; kd++)
#pragma unroll
                for (int mt = 0; mt < 4; mt++)
#pragma unroll
                    for (int nt = 0; nt < 2; nt++)
                        sacc[mt][nt] = MFMA16(ak[kd][mt], bq[nt][kd], sacc[mt][nt]);

            // softmax numerator (fixed max 0), packed directly into PV A-fragments.
            // sacc[mt][nt][r] = S[k = k0 + (mt>>1)*32 + 8g + 4*(mt&1) + r][q = nt*16+ln]
            bool needs_mask = (k0 + 63 > q0 + wq * 32);
            f16x8 ap[2][2];
#pragma unroll
            for (int nt = 0; nt < 2; nt++) {
                int q = q0 + wq * 32 + nt * 16 + ln;
#pragma unroll
                for (int mt = 0; mt < 4; mt++) {
                    int kb = mt >> 1, hi4 = (mt & 1) * 4;
#pragma unroll
                    for (int r = 0; r < 4; r++) {
                        float e;
                        if (needs_mask) {
                            int kk = k0 + kb * 32 + hi4 + 8 * g + r;
                            e = __builtin_amdgcn_exp2f(
                                fmaf(sacc[mt][nt][r], C_SCL, (kk > q) ? C_MSK : 0.f));
                        } else {
                            e = __builtin_amdgcn_exp2f(sacc[mt][nt][r] * C_SCL);
                        }
                        ap[nt][kb][hi4 + r] = (f16)e;
                    }
                }
            }

            // O += P.V ; rowsum += P.1  (P entirely in registers)
#pragma unroll
            for (int kk = 0; kk < 2; kk++) {
                f16x8 bv[4];
#pragma unroll
                for (int dt = 0; dt < 4; dt++)
                    bv[dt] = *(const f16x8*)&Vs[cur][dt * 16 + ln][kk * 32 + g8];
#pragma unroll
                for (int nt = 0; nt < 2; nt++) {
#pragma unroll
                    for (int dt = 0; dt < 4; dt++)
                        oacc[nt][dt] = MFMA16(ap[nt][kk], bv[dt], oacc[nt][dt]);
                    osum[nt] = MFMA16(ap[nt][kk], ones, osum[nt]);
                }
            }
        }
        __syncthreads();  // buf[cur^1] staged; all waves done reading buf[cur]
    }

    // epilogue: osum C-layout row = 4g+r matches oacc rows exactly
#pragma unroll
    for (int nt = 0; nt < 2; nt++)
#pragma unroll
        for (int r = 0; r < 4; r++) {
            float inv = __builtin_amdgcn_rcpf(osum[nt][r]);
            int row = b * 2048 + q0 + wq * 32 + nt * 16 + rg + r;
#pragma unroll
            for (int dt = 0; dt < 4; dt++)
                Ob[(size_t)row * 1024 + h * 64 + dt * 16 + ln] =
                    (f16)(oacc[nt][dt][r] * inv);
        }
#undef LOADT
#undef STORET
}

// ---------------- host launch ----------------
extern "C" void kernel_launch(void* const* d_in, const int* in_sizes, int n_in,
                              void* d_out, int out_size, void* d_ws, size_t ws_size,
                              hipStream_t stream) {
    const float* x = (const float*)d_in[0];
    const float* Wq = (const float*)d_in[1];
    const float* Wk = (const float*)d_in[2];
    const float* Wv = (const float*)d_in[3];
    const float* Wr = (const float*)d_in[4];
    float* out = (float*)d_out;

    f16* ws = (f16*)d_ws;
    f16* xb    = ws;                    // 8192*1024
    f16* Wqkvt = xb + 8388608;          // 3072*1024
    f16* Wrt   = Wqkvt + 3145728;       // 1024*1024
    f16* QKVb  = Wrt + 1048576;         // 8192*3072
    f16* Vtb   = QKVb + 25165824;       // 64bh * 64d * 2048s
    f16* Obuf  = Vtb + 8388608;         // 8192*1024

    k_convert<<<8192, 256, 0, stream>>>(x, xb, 8388608);
    dim3 tb(32, 8);
    k_transpose_w4<<<dim3(32, 32, 4), tb, 0, stream>>>(Wq, Wk, Wv, Wr, Wqkvt, Wrt);
    k_gemm_bt<true><<<dim3(24, 64), 256, 0, stream>>>(xb, Wqkvt, QKVb, 8192, 3072, 1024);
    k_transpose_v<<<dim3(64, 2, 64), tb, 0, stream>>>(QKVb, Vtb);
    k_attn<<<dim3(64, 16), 256, 0, stream>>>(QKVb, Vtb, Obuf);
    k_gemm_bt<false><<<dim3(8, 64), 256, 0, stream>>>(Obuf, Wrt, out, 8192, 1024, 1024);
}

// Round 5
// 291.821 us; speedup vs baseline: 1.8854x; 1.0184x over previous
//
#include <hip/hip_runtime.h>

typedef _Float16 f16;
typedef _Float16 f16x8 __attribute__((ext_vector_type(8)));
typedef _Float16 f16x4 __attribute__((ext_vector_type(4)));
typedef float f32x4 __attribute__((ext_vector_type(4)));

#define MFMA16(A, B, C) __builtin_amdgcn_mfma_f32_16x16x32_f16((A), (B), (C), 0, 0, 0)

// async global->LDS, 16B per lane, dest = wave-uniform base + lane*16
__device__ __forceinline__ void async16(void* lds, const void* gp) {
    __builtin_amdgcn_global_load_lds(
        (__attribute__((address_space(1))) void*)(gp),
        (__attribute__((address_space(3))) void*)(lds), 16, 0, 0);
}

// ---------------- fp32 -> fp16 cast (vectorized) ----------------
__global__ __launch_bounds__(256) void k_convert(const float* __restrict__ in,
                                                 f16* __restrict__ out, int n) {
    int i = (blockIdx.x * 256 + threadIdx.x) * 4;
    if (i + 3 < n) {
        float4 v = *(const float4*)(in + i);
        f16x4 o = {(f16)v.x, (f16)v.y, (f16)v.z, (f16)v.w};
        *(f16x4*)(out + i) = o;
    }
}

// ---------------- transpose + cast all four 1024x1024 weights in one launch ----------------
__global__ __launch_bounds__(256) void k_transpose_w4(const float* __restrict__ Wq,
                                                      const float* __restrict__ Wk,
                                                      const float* __restrict__ Wv,
                                                      const float* __restrict__ Wr,
                                                      f16* __restrict__ Wqkvt,
                                                      f16* __restrict__ Wrt) {
    __shared__ float tile[32][33];
    int z = blockIdx.z;
    const float* W = (z == 0) ? Wq : (z == 1) ? Wk : (z == 2) ? Wv : Wr;
    f16* Wt = (z == 3) ? Wrt : Wqkvt + z * 1048576;
    int c0 = blockIdx.x * 32, r0 = blockIdx.y * 32;
    int tx = threadIdx.x, ty = threadIdx.y;  // 32 x 8
#pragma unroll
    for (int j = 0; j < 32; j += 8)
        tile[ty + j][tx] = W[(r0 + ty + j) * 1024 + c0 + tx];
    __syncthreads();
#pragma unroll
    for (int j = 0; j < 32; j += 8)
        Wt[(c0 + ty + j) * 1024 + r0 + tx] = (f16)tile[tx][ty + j];
}

// ---------------- transpose V slice of QKV into Vt[bh][d][s] ----------------
__global__ __launch_bounds__(256) void k_transpose_v(const f16* __restrict__ QKV,
                                                     f16* __restrict__ Vt) {
    __shared__ f16 tile[32][33];
    int s0 = blockIdx.x * 32;
    int d0 = blockIdx.y * 32;
    int bh = blockIdx.z;
    int b = bh >> 4, h = bh & 15;
    int tx = threadIdx.x, ty = threadIdx.y;  // 32 x 8
#pragma unroll
    for (int j = 0; j < 32; j += 8)
        tile[ty + j][tx] = QKV[(b * 2048 + s0 + ty + j) * 3072 + 2048 + h * 64 + d0 + tx];
    __syncthreads();
#pragma unroll
    for (int j = 0; j < 32; j += 8)
        Vt[(bh * 64 + d0 + ty + j) * 2048 + s0 + tx] = tile[tx][ty + j];
}

// ---------------- GEMM: C[M][N] = A[M][K] * Bt[N][K]^T, async-LDS staging ----------------
// 128x128 tile, BK=32, 256 threads. Unpadded LDS; 16B chunk c of row r stored at slot
// c ^ ((r>>1)&3): async writes are lane-contiguous, frag reads per-beat conflict-free.
template <bool OUT_F16>
__global__ __launch_bounds__(256) void k_gemm_bt(const f16* __restrict__ A,
                                                 const f16* __restrict__ Bt,
                                                 void* __restrict__ Cv,
                                                 int M, int N, int K) {
    __shared__ f16 As[128][32];
    __shared__ f16 Bs[128][32];
    int t = threadIdx.x;
    int lane = t & 63, w = t >> 6;
    int wm = (w >> 1) * 64, wn = (w & 1) * 64;
    int m0 = blockIdx.y * 128, n0 = blockIdx.x * 128;
    int ln = lane & 15, g = lane >> 4;

    // async staging map: two 64-chunk instructions per matrix per wave
    int lin0 = w * 128 + lane, lin1 = lin0 + 64;
    int r0 = lin0 >> 2, c0 = (lin0 & 3) ^ ((r0 >> 1) & 3);
    int r1 = lin1 >> 2, c1 = (lin1 & 3) ^ ((r1 >> 1) & 3);
    const f16* gA0 = A + (size_t)(m0 + r0) * K + c0 * 8;
    const f16* gA1 = A + (size_t)(m0 + r1) * K + c1 * 8;
    const f16* gB0 = Bt + (size_t)(n0 + r0) * K + c0 * 8;
    const f16* gB1 = Bt + (size_t)(n0 + r1) * K + c1 * 8;
    f16* lA0 = &As[0][0] + w * 1024;
    f16* lB0 = &Bs[0][0] + w * 1024;

    f32x4 acc[4][4] = {};
    int sw = (ln >> 1) & 3;

    for (int k0 = 0; k0 < K; k0 += 32) {
        __syncthreads();
        async16(lA0, gA0 + k0);
        async16(lA0 + 512, gA1 + k0);
        async16(lB0, gB0 + k0);
        async16(lB0 + 512, gB1 + k0);
        __syncthreads();
        f16x8 af[4], bf[4];
#pragma unroll
        for (int i = 0; i < 4; i++) {
            af[i] = *(const f16x8*)&As[wm + i * 16 + ln][(g ^ sw) * 8];
            bf[i] = *(const f16x8*)&Bs[wn + i * 16 + ln][(g ^ sw) * 8];
        }
#pragma unroll
        for (int mt = 0; mt < 4; mt++)
#pragma unroll
            for (int nt = 0; nt < 4; nt++)
                acc[mt][nt] = MFMA16(af[mt], bf[nt], acc[mt][nt]);
    }

    int rg = g * 4;
#pragma unroll
    for (int mt = 0; mt < 4; mt++)
#pragma unroll
        for (int nt = 0; nt < 4; nt++)
#pragma unroll
            for (int r = 0; r < 4; r++) {
                int row = m0 + wm + mt * 16 + rg + r;
                int col = n0 + wn + nt * 16 + ln;
                float v = acc[mt][nt][r];
                if (OUT_F16)
                    ((f16*)Cv)[(size_t)row * N + col] = (f16)v;
                else
                    ((float*)Cv)[(size_t)row * N + col] = v;
            }
}

// ---------------- flash attention v8: in-register P + uniform split-k ----------------
// v7 inner loop (verified round 4) + round-1's verified split-k decomposition:
// fixed-max-0 softmax => partial numerators/rowsums exactly additive. Block pi:
//   phase 0: qt=15-pi, k-tiles [0, 16-pi)        (16-pi tiles, contains diagonal)
//   phase 1: qt=pi,    k-tiles [pi+1, 2pi+2)     (pi+1 tiles)
// -> 1024 blocks x uniform 17 tiles: balanced under ANY dispatch->CU mapping (round-4
// lesson: occupancy 15.7% came from same-qt blocks landing on one CU under XCD-RR).
// Grid stays bh-major (x=bh): round 4 measured FETCH 147->26MB from this L2 locality.
// In-register P: physical LDS row P holds global K-row rho^-1(P) (global-side perm at
// staging); S^T C-layout lands k = kb*32+8g+4hi+r = PV A-fragment order. P never
// touches LDS. Double-buffered K/V, one barrier per tile. launch_bounds (256,2):
// compiler takes ~100 VGPR spill-free (round-3 lesson: forcing 4 spills 620MB);
// hardware still co-schedules 4 blocks/CU (100<=128-class, LDS 4x36.9KB<160KB).
__global__ __launch_bounds__(256, 2) void k_attn(const f16* __restrict__ QKV,
                                                 const f16* __restrict__ Vt,
                                                 f16* __restrict__ Opart,
                                                 float* __restrict__ Rsum) {
    __shared__ f16 Ks[2][64][72];
    __shared__ f16 Vs[2][64][72];  // V^T tile: [d][k]
    int bh = blockIdx.x, pi = blockIdx.y;  // pi 0..15
    int b = bh >> 4, h = bh & 15;
    int t = threadIdx.x, lane = t & 63, wq = t >> 6;
    int ln = lane & 15, g = lane >> 4, g8 = g * 8, rg = g * 4;

    // staging coords: two K chunks + two V chunks per thread per tile
    int kr0 = t >> 3, kc0 = (t & 7) * 8;   // physical rows 0..31 (natural write order)
    int kr1 = kr0 + 32;                    // physical rows 32..63
    // global K-row to load = rho^-1(physical row); bit5 preserved
    int kg0 = ((kr0 & 16) >> 2) | ((kr0 & 12) << 1) | (kr0 & 3);
    int kg1 = kg0 + 32;
    const f16* Kbase = QKV + (size_t)b * 2048 * 3072 + 1024 + h * 64;
    const f16* Vbase = Vt + (size_t)bh * 64 * 2048;

    const float C_SCL = 0.18033688f;   // 0.125 * log2(e)
    const float C_MSK = -72.134752f;   // -50 * log2(e)
    f16x8 ones;
#pragma unroll
    for (int j = 0; j < 8; j++) ones[j] = (f16)1.f;

    int nk0 = 16 - pi;  // phase-0 tile count; total tiles always 17

    int4 rk0, rk1, rv0, rv1;
#define LOADT(j)                                                          \
    do {                                                                  \
        int j_ = (j);                                                     \
        int kt_ = (j_ < nk0) ? j_ : j_ - nk0 + pi + 1;                    \
        size_t kO = (size_t)kt_ * 64;                                     \
        rk0 = *(const int4*)(Kbase + (kO + kg0) * 3072 + kc0);            \
        rk1 = *(const int4*)(Kbase + (kO + kg1) * 3072 + kc0);            \
        rv0 = *(const int4*)(Vbase + (size_t)kr0 * 2048 + kO + kc0);      \
        rv1 = *(const int4*)(Vbase + (size_t)kr1 * 2048 + kO + kc0);      \
    } while (0)
#define STORET(bi)                                                        \
    do {                                                                  \
        *(int4*)&Ks[bi][kr0][kc0] = rk0;                                  \
        *(int4*)&Ks[bi][kr1][kc0] = rk1;                                  \
        *(int4*)&Vs[bi][kr0][kc0] = rv0;                                  \
        *(int4*)&Vs[bi][kr1][kc0] = rv1;                                  \
    } while (0)

    LOADT(0);
    STORET(0);
    LOADT(1);
    __syncthreads();

    int i = 0;
    for (int phase = 0; phase < 2; phase++) {
        int qt  = phase ? pi : 15 - pi;
        int ktB = phase ? pi + 1 : 0;
        int ktE = phase ? 2 * pi + 2 : 16 - pi;
        int q0 = qt * 128;

        f16x8 bq[2][2];
#pragma unroll
        for (int nt = 0; nt < 2; nt++)
#pragma unroll
            for (int kd = 0; kd < 2; kd++)
                bq[nt][kd] = *(const f16x8*)(QKV +
                    (size_t)(b * 2048 + q0 + wq * 32 + nt * 16 + ln) * 3072 +
                    h * 64 + kd * 32 + g8);

        f32x4 oacc[2][4] = {};
        f32x4 osum[2] = {};

        for (int kt = ktB; kt < ktE; kt++, i++) {
            int cur = i & 1;
            int k0 = kt * 64;
            // tile fully above this wave's diagonal -> contributes ~e^-50 ~ 0
            bool active = (k0 <= q0 + wq * 32 + 31);  // wave-uniform

            f16x8 ak[2][4];
            if (active) {
#pragma unroll
                for (int kd = 0; kd < 2; kd++)
#pragma unroll
                    for (int mt = 0; mt < 4; mt++)
                        ak[kd][mt] = *(const f16x8*)&Ks[cur][mt * 16 + ln][kd * 32 + g8];
            }
            // stage next tile into other buffer (safe: all waves finished reading it
            // before last barrier), then prefetch the tile after that from global.
            if (i + 1 < 17) STORET(cur ^ 1);
            if (i + 2 < 17) LOADT(i + 2);

            if (active) {
                // S^T tile: D[m=physical k-row][n=q]; physical row P holds k = rho^-1(P)
                f32x4 sacc[4][2] = {};
#pragma unroll
                for (int kd = 0; kd < 2; kd++)
#pragma unroll
                    for (int mt = 0; mt < 4; mt++)
#pragma unroll
                        for (int nt = 0; nt < 2; nt++)
                            sacc[mt][nt] = MFMA16(ak[kd][mt], bq[nt][kd], sacc[mt][nt]);

                // softmax numerator (fixed max 0), packed directly into PV A-fragments.
                // sacc[mt][nt][r] = S[k = k0 + (mt>>1)*32 + 8g + 4*(mt&1) + r][q=nt*16+ln]
                bool needs_mask = (k0 + 63 > q0 + wq * 32);
                f16x8 ap[2][2];
#pragma unroll
                for (int nt = 0; nt < 2; nt++) {
                    int q = q0 + wq * 32 + nt * 16 + ln;
#pragma unroll
                    for (int mt = 0; mt < 4; mt++) {
                        int kb = mt >> 1, hi4 = (mt & 1) * 4;
#pragma unroll
                        for (int r = 0; r < 4; r++) {
                            float e;
                            if (needs_mask) {
                                int kk = k0 + kb * 32 + hi4 + 8 * g + r;
                                e = __builtin_amdgcn_exp2f(
                                    fmaf(sacc[mt][nt][r], C_SCL, (kk > q) ? C_MSK : 0.f));
                            } else {
                                e = __builtin_amdgcn_exp2f(sacc[mt][nt][r] * C_SCL);
                            }
                            ap[nt][kb][hi4 + r] = (f16)e;
                        }
                    }
                }

                // O += P.V ; rowsum += P.1  (P entirely in registers)
#pragma unroll
                for (int kk = 0; kk < 2; kk++) {
                    f16x8 bv[4];
#pragma unroll
                    for (int dt = 0; dt < 4; dt++)
                        bv[dt] = *(const f16x8*)&Vs[cur][dt * 16 + ln][kk * 32 + g8];
#pragma unroll
                    for (int nt = 0; nt < 2; nt++) {
#pragma unroll
                        for (int dt = 0; dt < 4; dt++)
                            oacc[nt][dt] = MFMA16(ap[nt][kk], bv[dt], oacc[nt][dt]);
                        osum[nt] = MFMA16(ap[nt][kk], ones, osum[nt]);
                    }
                }
            }
            __syncthreads();  // buf[cur^1] staged; all waves done reading buf[cur]
        }

        // epilogue: write normalized partial + rowsum. osum C-layout row = 4g+r matches
        // oacc rows exactly. Fully-skipped waves (rs=0) guarded -> write 0.
        int u = (bh * 16 + qt) * 2 + phase;
#pragma unroll
        for (int nt = 0; nt < 2; nt++)
#pragma unroll
            for (int r = 0; r < 4; r++) {
                float rs = osum[nt][r];
                float inv = __builtin_amdgcn_rcpf(fmaxf(rs, 1e-30f));
                int q = wq * 32 + nt * 16 + rg + r;
                if (ln == 0) Rsum[u * 128 + q] = rs;
#pragma unroll
                for (int dt = 0; dt < 4; dt++)
                    Opart[(size_t)u * 8192 + q * 64 + dt * 16 + ln] =
                        (f16)(oacc[nt][dt][r] * inv);
            }
    }
#undef LOADT
#undef STORET
}

// ---------------- merge split-k partials: O = (rs0*O0 + rs1*O1)/(rs0+rs1) ----------------
__global__ __launch_bounds__(256) void k_merge(const f16* __restrict__ Op,
                                               const float* __restrict__ Rs,
                                               f16* __restrict__ Ob) {
    int idx = blockIdx.x * 256 + threadIdx.x;  // 64bh*16qt*128q*8chunks = 1,048,576
    int d8 = idx & 7;
    int q  = (idx >> 3) & 127;
    int qt = (idx >> 10) & 15;
    int bh = idx >> 14;
    int b = bh >> 4, hd = bh & 15;
    int u0 = (bh * 16 + qt) * 2;
    float rs0 = Rs[u0 * 128 + q], rs1 = Rs[(u0 + 1) * 128 + q];
    float inv = __builtin_amdgcn_rcpf(rs0 + rs1);  // rs0 > 0 always (diagonal in half 0)
    f16x8 o0 = *(const f16x8*)(Op + (size_t)u0 * 8192 + q * 64 + d8 * 8);
    f16x8 o1 = *(const f16x8*)(Op + (size_t)(u0 + 1) * 8192 + q * 64 + d8 * 8);
    f16x8 o;
#pragma unroll
    for (int j = 0; j < 8; j++)
        o[j] = (f16)((rs0 * (float)o0[j] + rs1 * (float)o1[j]) * inv);
    *(f16x8*)(Ob + (size_t)(b * 2048 + qt * 128 + q) * 1024 + hd * 64 + d8 * 8) = o;
}

// ---------------- host launch ----------------
extern "C" void kernel_launch(void* const* d_in, const int* in_sizes, int n_in,
                              void* d_out, int out_size, void* d_ws, size_t ws_size,
                              hipStream_t stream) {
    const float* x = (const float*)d_in[0];
    const float* Wq = (const float*)d_in[1];
    const float* Wk = (const float*)d_in[2];
    const float* Wv = (const float*)d_in[3];
    const float* Wr = (const float*)d_in[4];
    float* out = (float*)d_out;

    f16* ws = (f16*)d_ws;
    f16* xb    = ws;                    // 8192*1024
    f16* Wqkvt = xb + 8388608;          // 3072*1024
    f16* Wrt   = Wqkvt + 3145728;       // 1024*1024
    f16* QKVb  = Wrt + 1048576;         // 8192*3072
    f16* Vtb   = QKVb + 25165824;       // 64bh * 64d * 2048s
    f16* Obuf  = Vtb + 8388608;         // 8192*1024
    f16* Opart = Obuf + 8388608;        // 2048 units * 128q * 64d
    float* Rsum = (float*)(Opart + 16777216);  // 2048 units * 128q

    k_convert<<<8192, 256, 0, stream>>>(x, xb, 8388608);
    dim3 tb(32, 8);
    k_transpose_w4<<<dim3(32, 32, 4), tb, 0, stream>>>(Wq, Wk, Wv, Wr, Wqkvt, Wrt);
    k_gemm_bt<true><<<dim3(24, 64), 256, 0, stream>>>(xb, Wqkvt, QKVb, 8192, 3072, 1024);
    k_transpose_v<<<dim3(64, 2, 64), tb, 0, stream>>>(QKVb, Vtb);
    k_attn<<<dim3(64, 16), 256, 0, stream>>>(QKVb, Vtb, Opart, Rsum);
    k_merge<<<4096, 256, 0, stream>>>(Opart, Rsum, Obuf);
    k_gemm_bt<false><<<dim3(8, 64), 256, 0, stream>>>(Obuf, Wrt, out, 8192, 1024, 1024);
}

// Round 6
// 285.471 us; speedup vs baseline: 1.9273x; 1.0222x over previous
//
#include <hip/hip_runtime.h>

typedef _Float16 f16;
typedef _Float16 f16x8 __attribute__((ext_vector_type(8)));
typedef _Float16 f16x4 __attribute__((ext_vector_type(4)));
typedef float f32x4 __attribute__((ext_vector_type(4)));

#define MFMA16(A, B, C) __builtin_amdgcn_mfma_f32_16x16x32_f16((A), (B), (C), 0, 0, 0)

// async global->LDS, 16B per lane, dest = wave-uniform base + lane*16
__device__ __forceinline__ void async16(void* lds, const void* gp) {
    __builtin_amdgcn_global_load_lds(
        (__attribute__((address_space(1))) void*)(gp),
        (__attribute__((address_space(3))) void*)(lds), 16, 0, 0);
}

// ---------------- fp32 -> fp16 cast (vectorized) ----------------
__global__ __launch_bounds__(256) void k_convert(const float* __restrict__ in,
                                                 f16* __restrict__ out, int n) {
    int i = (blockIdx.x * 256 + threadIdx.x) * 4;
    if (i + 3 < n) {
        float4 v = *(const float4*)(in + i);
        f16x4 o = {(f16)v.x, (f16)v.y, (f16)v.z, (f16)v.w};
        *(f16x4*)(out + i) = o;
    }
}

// ---------------- transpose + cast all four 1024x1024 weights in one launch ----------------
__global__ __launch_bounds__(256) void k_transpose_w4(const float* __restrict__ Wq,
                                                      const float* __restrict__ Wk,
                                                      const float* __restrict__ Wv,
                                                      const float* __restrict__ Wr,
                                                      f16* __restrict__ Wqkvt,
                                                      f16* __restrict__ Wrt) {
    __shared__ float tile[32][33];
    int z = blockIdx.z;
    const float* W = (z == 0) ? Wq : (z == 1) ? Wk : (z == 2) ? Wv : Wr;
    f16* Wt = (z == 3) ? Wrt : Wqkvt + z * 1048576;
    int c0 = blockIdx.x * 32, r0 = blockIdx.y * 32;
    int tx = threadIdx.x, ty = threadIdx.y;  // 32 x 8
#pragma unroll
    for (int j = 0; j < 32; j += 8)
        tile[ty + j][tx] = W[(r0 + ty + j) * 1024 + c0 + tx];
    __syncthreads();
#pragma unroll
    for (int j = 0; j < 32; j += 8)
        Wt[(c0 + ty + j) * 1024 + r0 + tx] = (f16)tile[tx][ty + j];
}

// ---------------- transpose V slice of QKV into Vt[bh][d][s] ----------------
__global__ __launch_bounds__(256) void k_transpose_v(const f16* __restrict__ QKV,
                                                     f16* __restrict__ Vt) {
    __shared__ f16 tile[32][33];
    int s0 = blockIdx.x * 32;
    int d0 = blockIdx.y * 32;
    int bh = blockIdx.z;
    int b = bh >> 4, h = bh & 15;
    int tx = threadIdx.x, ty = threadIdx.y;  // 32 x 8
#pragma unroll
    for (int j = 0; j < 32; j += 8)
        tile[ty + j][tx] = QKV[(b * 2048 + s0 + ty + j) * 3072 + 2048 + h * 64 + d0 + tx];
    __syncthreads();
#pragma unroll
    for (int j = 0; j < 32; j += 8)
        Vt[(bh * 64 + d0 + ty + j) * 2048 + s0 + tx] = tile[tx][ty + j];
}

// ---------------- GEMM: C[M][N] = A[M][K] * Bt[N][K]^T, async-LDS staging ----------------
// 128x128 tile, BK=32, 256 threads. Unpadded LDS; 16B chunk c of row r stored at slot
// c ^ ((r>>1)&3): async writes are lane-contiguous, frag reads per-beat conflict-free.
template <bool OUT_F16>
__global__ __launch_bounds__(256) void k_gemm_bt(const f16* __restrict__ A,
                                                 const f16* __restrict__ Bt,
                                                 void* __restrict__ Cv,
                                                 int M, int N, int K) {
    __shared__ f16 As[128][32];
    __shared__ f16 Bs[128][32];
    int t = threadIdx.x;
    int lane = t & 63, w = t >> 6;
    int wm = (w >> 1) * 64, wn = (w & 1) * 64;
    int m0 = blockIdx.y * 128, n0 = blockIdx.x * 128;
    int ln = lane & 15, g = lane >> 4;

    // async staging map: two 64-chunk instructions per matrix per wave
    int lin0 = w * 128 + lane, lin1 = lin0 + 64;
    int r0 = lin0 >> 2, c0 = (lin0 & 3) ^ ((r0 >> 1) & 3);
    int r1 = lin1 >> 2, c1 = (lin1 & 3) ^ ((r1 >> 1) & 3);
    const f16* gA0 = A + (size_t)(m0 + r0) * K + c0 * 8;
    const f16* gA1 = A + (size_t)(m0 + r1) * K + c1 * 8;
    const f16* gB0 = Bt + (size_t)(n0 + r0) * K + c0 * 8;
    const f16* gB1 = Bt + (size_t)(n0 + r1) * K + c1 * 8;
    f16* lA0 = &As[0][0] + w * 1024;
    f16* lB0 = &Bs[0][0] + w * 1024;

    f32x4 acc[4][4] = {};
    int sw = (ln >> 1) & 3;

    for (int k0 = 0; k0 < K; k0 += 32) {
        __syncthreads();
        async16(lA0, gA0 + k0);
        async16(lA0 + 512, gA1 + k0);
        async16(lB0, gB0 + k0);
        async16(lB0 + 512, gB1 + k0);
        __syncthreads();
        f16x8 af[4], bf[4];
#pragma unroll
        for (int i = 0; i < 4; i++) {
            af[i] = *(const f16x8*)&As[wm + i * 16 + ln][(g ^ sw) * 8];
            bf[i] = *(const f16x8*)&Bs[wn + i * 16 + ln][(g ^ sw) * 8];
        }
#pragma unroll
        for (int mt = 0; mt < 4; mt++)
#pragma unroll
            for (int nt = 0; nt < 4; nt++)
                acc[mt][nt] = MFMA16(af[mt], bf[nt], acc[mt][nt]);
    }

    int rg = g * 4;
#pragma unroll
    for (int mt = 0; mt < 4; mt++)
#pragma unroll
        for (int nt = 0; nt < 4; nt++)
#pragma unroll
            for (int r = 0; r < 4; r++) {
                int row = m0 + wm + mt * 16 + rg + r;
                int col = n0 + wn + nt * 16 + ln;
                float v = acc[mt][nt][r];
                if (OUT_F16)
                    ((f16*)Cv)[(size_t)row * N + col] = (f16)v;
                else
                    ((float*)Cv)[(size_t)row * N + col] = v;
            }
}

// ---------------- flash attention v9: async-LDS staging, in-register P, split-k --------
// Same math as v8 (verified round 5, bit-identical values). Staging now uses
// global_load_lds (async16): no register staging, no ds_writes, no staging VGPRs.
// LDS unpadded [64][64] (32KB total -> 5 blocks/CU by LDS). Since global_load_lds
// writes linearly (base + lane*16), ALL layout permutations live on the per-lane
// GLOBAL source address (Guideline 21):
//   - K-row permutation rho^-1 (in-register P): phys row r holds global K-row
//     glob(r) = (r&32)|((r&16)>>2)|((r&12)<<1)|(r&3); S^T C-layout then lands
//     k = (mt>>1)*32 + 8g + 4*(mt&1) + r = the PV A-fragment order (verified r4/r5).
//   - bank swizzle: phys 16B-chunk cp of row r holds logical chunk cp^(r&7);
//     reads use chunk ((kd*4+g)^(ln&7)) -> every bank gets exactly 8 accesses per
//     wave ds_read_b128 = minimum -> conflict-free. Permutation stays inside each
//     128B row segment -> global coalescing unchanged.
// Pipeline: at tile i issue async16 x4 into buf^1 (tile i+1); the per-tile
// __syncthreads drains vmcnt (compiler emits s_waitcnt vmcnt(0) before s_barrier).
// Split-k (verified r5): block pi: phase0 qt=15-pi kt[0,16-pi), phase1 qt=pi
// kt[pi+1,2pi+2) -> 1024 uniform 17-tile blocks; partials merged by k_merge.
__global__ __launch_bounds__(256, 2) void k_attn(const f16* __restrict__ QKV,
                                                 const f16* __restrict__ Vt,
                                                 f16* __restrict__ Opart,
                                                 float* __restrict__ Rsum) {
    __shared__ f16 Ks[2][64][64];
    __shared__ f16 Vs[2][64][64];  // V^T tile: [d][k]
    int bh = blockIdx.x, pi = blockIdx.y;  // pi 0..15
    int b = bh >> 4, h = bh & 15;
    int t = threadIdx.x, lane = t & 63, wq = t >> 6;
    int ln = lane & 15, g = lane >> 4, g8 = g * 8, rg = g * 4;
    int sx = ln & 7;  // read-side chunk xor

    // ---- async staging geometry: wave wq, instr i in {0,1} covers phys rows
    // i*32 + wq*8 .. +8; lane l -> row += l>>3, phys chunk cp = l&7 ----
    int r0 = wq * 8 + (lane >> 3);        // phys row for instr 0 (0..31)
    int cp = lane & 7;
    int cl = (cp ^ (r0 & 7)) * 8;         // logical col (f16 elems) to fetch
    int gk0 = ((r0 & 16) >> 2) | ((r0 & 12) << 1) | (r0 & 3);  // glob(r0)
    const f16* Kb = QKV + (size_t)b * 2048 * 3072 + 1024 + h * 64;
    const f16* Vb = Vt + (size_t)bh * 64 * 2048;
    const f16* gK0 = Kb + (size_t)gk0 * 3072 + cl;
    const f16* gK1 = Kb + (size_t)(gk0 + 32) * 3072 + cl;
    const f16* gV0 = Vb + (size_t)r0 * 2048 + cl;
    const f16* gV1 = Vb + (size_t)(r0 + 32) * 2048 + cl;

    const float C_SCL = 0.18033688f;   // 0.125 * log2(e)
    const float C_MSK = -72.134752f;   // -50 * log2(e)
    f16x8 ones;
#pragma unroll
    for (int j = 0; j < 8; j++) ones[j] = (f16)1.f;

    int nk0 = 16 - pi;  // phase-0 tile count; total tiles always 17

#define ISSUE(bi, j)                                                      \
    do {                                                                  \
        int jj = (j);                                                     \
        int kt_ = (jj < nk0) ? jj : jj - nk0 + pi + 1;                    \
        size_t kO = (size_t)kt_ * 64;                                     \
        async16(&Ks[bi][wq * 8][0],      gK0 + kO * 3072);                \
        async16(&Ks[bi][32 + wq * 8][0], gK1 + kO * 3072);                \
        async16(&Vs[bi][wq * 8][0],      gV0 + kO);                       \
        async16(&Vs[bi][32 + wq * 8][0], gV1 + kO);                       \
    } while (0)

    ISSUE(0, 0);
    __syncthreads();  // barrier drains vmcnt -> tile 0 staged

    int i = 0;
    for (int phase = 0; phase < 2; phase++) {
        int qt  = phase ? pi : 15 - pi;
        int ktB = phase ? pi + 1 : 0;
        int ktE = phase ? 2 * pi + 2 : 16 - pi;
        int q0 = qt * 128;

        f16x8 bq[2][2];
#pragma unroll
        for (int nt = 0; nt < 2; nt++)
#pragma unroll
            for (int kd = 0; kd < 2; kd++)
                bq[nt][kd] = *(const f16x8*)(QKV +
                    (size_t)(b * 2048 + q0 + wq * 32 + nt * 16 + ln) * 3072 +
                    h * 64 + kd * 32 + g8);

        f32x4 oacc[2][4] = {};
        f32x4 osum[2] = {};

        for (int kt = ktB; kt < ktE; kt++, i++) {
            int cur = i & 1;
            int k0 = kt * 64;
            // tile fully above this wave's diagonal -> contributes ~e^-50 ~ 0
            bool active = (k0 <= q0 + wq * 32 + 31);  // wave-uniform

            // prefetch tile i+1 into the other buffer (all waves finished reading
            // it before the barrier that ended tile i-1); barrier below drains it.
            if (i + 1 < 17) ISSUE(cur ^ 1, i + 1);

            if (active) {
                // S^T tile: D[m=phys k-row][n=q]; phys row P holds k = glob(P)
                f16x8 ak[2][4];
#pragma unroll
                for (int kd = 0; kd < 2; kd++)
#pragma unroll
                    for (int mt = 0; mt < 4; mt++)
                        ak[kd][mt] = *(const f16x8*)
                            &Ks[cur][mt * 16 + ln][((kd * 4 + g) ^ sx) * 8];
                f32x4 sacc[4][2] = {};
#pragma unroll
                for (int kd = 0; kd < 2; kd++)
#pragma unroll
                    for (int mt = 0; mt < 4; mt++)
#pragma unroll
                        for (int nt = 0; nt < 2; nt++)
                            sacc[mt][nt] = MFMA16(ak[kd][mt], bq[nt][kd], sacc[mt][nt]);

                // softmax numerator (fixed max 0), packed directly into PV A-fragments.
                // sacc[mt][nt][r] = S[k = k0 + (mt>>1)*32 + 8g + 4*(mt&1) + r][q=nt*16+ln]
                bool needs_mask = (k0 + 63 > q0 + wq * 32);
                f16x8 ap[2][2];
#pragma unroll
                for (int nt = 0; nt < 2; nt++) {
                    int q = q0 + wq * 32 + nt * 16 + ln;
#pragma unroll
                    for (int mt = 0; mt < 4; mt++) {
                        int kb = mt >> 1, hi4 = (mt & 1) * 4;
#pragma unroll
                        for (int r = 0; r < 4; r++) {
                            float e;
                            if (needs_mask) {
                                int kk = k0 + kb * 32 + hi4 + 8 * g + r;
                                e = __builtin_amdgcn_exp2f(
                                    fmaf(sacc[mt][nt][r], C_SCL, (kk > q) ? C_MSK : 0.f));
                            } else {
                                e = __builtin_amdgcn_exp2f(sacc[mt][nt][r] * C_SCL);
                            }
                            ap[nt][kb][hi4 + r] = (f16)e;
                        }
                    }
                }

                // O += P.V ; rowsum += P.1  (P entirely in registers)
#pragma unroll
                for (int kk = 0; kk < 2; kk++) {
                    f16x8 bv[4];
#pragma unroll
                    for (int dt = 0; dt < 4; dt++)
                        bv[dt] = *(const f16x8*)
                            &Vs[cur][dt * 16 + ln][((kk * 4 + g) ^ sx) * 8];
#pragma unroll
                    for (int nt = 0; nt < 2; nt++) {
#pragma unroll
                        for (int dt = 0; dt < 4; dt++)
                            oacc[nt][dt] = MFMA16(ap[nt][kk], bv[dt], oacc[nt][dt]);
                        osum[nt] = MFMA16(ap[nt][kk], ones, osum[nt]);
                    }
                }
            }
            __syncthreads();  // drains tile i+1 staging; all waves done reading cur
        }

        // epilogue: write normalized partial + rowsum. osum C-layout row = 4g+r matches
        // oacc rows exactly. Fully-skipped waves (rs=0) guarded -> write 0.
        int u = (bh * 16 + qt) * 2 + phase;
#pragma unroll
        for (int nt = 0; nt < 2; nt++)
#pragma unroll
            for (int r = 0; r < 4; r++) {
                float rs = osum[nt][r];
                float inv = __builtin_amdgcn_rcpf(fmaxf(rs, 1e-30f));
                int q = wq * 32 + nt * 16 + rg + r;
                if (ln == 0) Rsum[u * 128 + q] = rs;
#pragma unroll
                for (int dt = 0; dt < 4; dt++)
                    Opart[(size_t)u * 8192 + q * 64 + dt * 16 + ln] =
                        (f16)(oacc[nt][dt][r] * inv);
            }
    }
#undef ISSUE
}

// ---------------- merge split-k partials: O = (rs0*O0 + rs1*O1)/(rs0+rs1) ----------------
__global__ __launch_bounds__(256) void k_merge(const f16* __restrict__ Op,
                                               const float* __restrict__ Rs,
                                               f16* __restrict__ Ob) {
    int idx = blockIdx.x * 256 + threadIdx.x;  // 64bh*16qt*128q*8chunks = 1,048,576
    int d8 = idx & 7;
    int q  = (idx >> 3) & 127;
    int qt = (idx >> 10) & 15;
    int bh = idx >> 14;
    int b = bh >> 4, hd = bh & 15;
    int u0 = (bh * 16 + qt) * 2;
    float rs0 = Rs[u0 * 128 + q], rs1 = Rs[(u0 + 1) * 128 + q];
    float inv = __builtin_amdgcn_rcpf(rs0 + rs1);  // rs0 > 0 always (diagonal in half 0)
    f16x8 o0 = *(const f16x8*)(Op + (size_t)u0 * 8192 + q * 64 + d8 * 8);
    f16x8 o1 = *(const f16x8*)(Op + (size_t)(u0 + 1) * 8192 + q * 64 + d8 * 8);
    f16x8 o;
#pragma unroll
    for (int j = 0; j < 8; j++)
        o[j] = (f16)((rs0 * (float)o0[j] + rs1 * (float)o1[j]) * inv);
    *(f16x8*)(Ob + (size_t)(b * 2048 + qt * 128 + q) * 1024 + hd * 64 + d8 * 8) = o;
}

// ---------------- host launch ----------------
extern "C" void kernel_launch(void* const* d_in, const int* in_sizes, int n_in,
                              void* d_out, int out_size, void* d_ws, size_t ws_size,
                              hipStream_t stream) {
    const float* x = (const float*)d_in[0];
    const float* Wq = (const float*)d_in[1];
    const float* Wk = (const float*)d_in[2];
    const float* Wv = (const float*)d_in[3];
    const float* Wr = (const float*)d_in[4];
    float* out = (float*)d_out;

    f16* ws = (f16*)d_ws;
    f16* xb    = ws;                    // 8192*1024
    f16* Wqkvt = xb + 8388608;          // 3072*1024
    f16* Wrt   = Wqkvt + 3145728;       // 1024*1024
    f16* QKVb  = Wrt + 1048576;         // 8192*3072
    f16* Vtb   = QKVb + 25165824;       // 64bh * 64d * 2048s
    f16* Obuf  = Vtb + 8388608;         // 8192*1024
    f16* Opart = Obuf + 8388608;        // 2048 units * 128q * 64d
    float* Rsum = (float*)(Opart + 16777216);  // 2048 units * 128q

    k_convert<<<8192, 256, 0, stream>>>(x, xb, 8388608);
    dim3 tb(32, 8);
    k_transpose_w4<<<dim3(32, 32, 4), tb, 0, stream>>>(Wq, Wk, Wv, Wr, Wqkvt, Wrt);
    k_gemm_bt<true><<<dim3(24, 64), 256, 0, stream>>>(xb, Wqkvt, QKVb, 8192, 3072, 1024);
    k_transpose_v<<<dim3(64, 2, 64), tb, 0, stream>>>(QKVb, Vtb);
    k_attn<<<dim3(64, 16), 256, 0, stream>>>(QKVb, Vtb, Opart, Rsum);
    k_merge<<<4096, 256, 0, stream>>>(Opart, Rsum, Obuf);
    k_gemm_bt<false><<<dim3(8, 64), 256, 0, stream>>>(Obuf, Wrt, out, 8192, 1024, 1024);
}

// Round 7
// 272.488 us; speedup vs baseline: 2.0191x; 1.0476x over previous
//
#include <hip/hip_runtime.h>

typedef _Float16 f16;
typedef _Float16 f16x8 __attribute__((ext_vector_type(8)));
typedef _Float16 f16x4 __attribute__((ext_vector_type(4)));
typedef float f32x4 __attribute__((ext_vector_type(4)));

#define MFMA16(A, B, C) __builtin_amdgcn_mfma_f32_16x16x32_f16((A), (B), (C), 0, 0, 0)

// async global->LDS, 16B per lane, dest = wave-uniform base + lane*16
__device__ __forceinline__ void async16(void* lds, const void* gp) {
    __builtin_amdgcn_global_load_lds(
        (__attribute__((address_space(1))) void*)(gp),
        (__attribute__((address_space(3))) void*)(lds), 16, 0, 0);
}

// ---------------- fused prep: fp32->fp16 cast of x  +  transpose-cast of 4 weights -----
// Block-uniform branch on blockIdx.x: [0,8192) convert 1024-elem chunks of x;
// [8192,12288) weight-transpose tiles (z = which weight, 32x32 tile). Saves one launch.
__global__ __launch_bounds__(256) void k_prep(const float* __restrict__ x,
                                              const float* __restrict__ Wq,
                                              const float* __restrict__ Wk,
                                              const float* __restrict__ Wv,
                                              const float* __restrict__ Wr,
                                              f16* __restrict__ xb,
                                              f16* __restrict__ Wqkvt,
                                              f16* __restrict__ Wrt) {
    __shared__ float tile[32][33];
    int bid = blockIdx.x;
    if (bid < 8192) {
        int i = (bid * 256 + threadIdx.x) * 4;  // 8192*256*4 = 8388608 exactly
        float4 v = *(const float4*)(x + i);
        f16x4 o = {(f16)v.x, (f16)v.y, (f16)v.z, (f16)v.w};
        *(f16x4*)(xb + i) = o;
    } else {
        int wid = bid - 8192;  // [0,4096)
        int z = wid >> 10;
        int tid = wid & 1023;
        const float* W = (z == 0) ? Wq : (z == 1) ? Wk : (z == 2) ? Wv : Wr;
        f16* Wt = (z == 3) ? Wrt : Wqkvt + z * 1048576;
        int c0 = (tid & 31) * 32, r0 = (tid >> 5) * 32;
        int tx = threadIdx.x & 31, ty = threadIdx.x >> 5;  // 32 x 8
#pragma unroll
        for (int j = 0; j < 32; j += 8)
            tile[ty + j][tx] = W[(r0 + ty + j) * 1024 + c0 + tx];
        __syncthreads();
#pragma unroll
        for (int j = 0; j < 32; j += 8)
            Wt[(c0 + ty + j) * 1024 + r0 + tx] = (f16)tile[tx][ty + j];
    }
}

// ---------------- transpose V slice of QKV into Vt[bh][d][s] ----------------
__global__ __launch_bounds__(256) void k_transpose_v(const f16* __restrict__ QKV,
                                                     f16* __restrict__ Vt) {
    __shared__ f16 tile[32][33];
    int s0 = blockIdx.x * 32;
    int d0 = blockIdx.y * 32;
    int bh = blockIdx.z;
    int b = bh >> 4, h = bh & 15;
    int tx = threadIdx.x, ty = threadIdx.y;  // 32 x 8
#pragma unroll
    for (int j = 0; j < 32; j += 8)
        tile[ty + j][tx] = QKV[(b * 2048 + s0 + ty + j) * 3072 + 2048 + h * 64 + d0 + tx];
    __syncthreads();
#pragma unroll
    for (int j = 0; j < 32; j += 8)
        Vt[(bh * 64 + d0 + ty + j) * 2048 + s0 + tx] = tile[tx][ty + j];
}

// ---------------- GEMM v2: 128x128 tile, BK=32, double-buffered async-LDS pipeline -----
// Same fragment/staging maps as the round-6 kernel (verified), now with 2 LDS buffers and
// ONE barrier per K-step: issue next tile's global_load_lds into buf^1 BEFORE computing
// buf (load latency hides under ds_read+MFMA); the end-of-step __syncthreads drains
// vmcnt -> next buffer fully staged (RAW), and the previous step's barrier ordered all
// reads of buf^1 before this step's writes (WAR). Pattern harness-verified in k_attn v9.
// Unpadded LDS; 16B chunk c of row r at slot c ^ ((r>>1)&3) via pre-swizzled global src.
template <bool OUT_F16>
__global__ __launch_bounds__(256) void k_gemm_bt(const f16* __restrict__ A,
                                                 const f16* __restrict__ Bt,
                                                 void* __restrict__ Cv,
                                                 int M, int N, int K) {
    __shared__ f16 As[2][128][32];
    __shared__ f16 Bs[2][128][32];
    int t = threadIdx.x;
    int lane = t & 63, w = t >> 6;
    int wm = (w >> 1) * 64, wn = (w & 1) * 64;
    int m0 = blockIdx.y * 128, n0 = blockIdx.x * 128;
    int ln = lane & 15, g = lane >> 4;

    // async staging map: two 64-chunk instructions per matrix per wave
    int lin0 = w * 128 + lane, lin1 = lin0 + 64;
    int r0 = lin0 >> 2, c0 = (lin0 & 3) ^ ((r0 >> 1) & 3);
    int r1 = lin1 >> 2, c1 = (lin1 & 3) ^ ((r1 >> 1) & 3);
    const f16* gA0 = A + (size_t)(m0 + r0) * K + c0 * 8;
    const f16* gA1 = A + (size_t)(m0 + r1) * K + c1 * 8;
    const f16* gB0 = Bt + (size_t)(n0 + r0) * K + c0 * 8;
    const f16* gB1 = Bt + (size_t)(n0 + r1) * K + c1 * 8;

    f32x4 acc[4][4] = {};
    int sw = (ln >> 1) & 3;

#define GISSUE(bi, kk)                                    \
    do {                                                  \
        f16* lA = &As[bi][0][0] + w * 1024;               \
        f16* lB = &Bs[bi][0][0] + w * 1024;               \
        async16(lA, gA0 + (kk));                          \
        async16(lA + 512, gA1 + (kk));                    \
        async16(lB, gB0 + (kk));                          \
        async16(lB + 512, gB1 + (kk));                    \
    } while (0)

    GISSUE(0, 0);
    __syncthreads();  // drains vmcnt -> tile 0 staged

    int cur = 0;
    for (int k0 = 0; k0 < K; k0 += 32) {
        if (k0 + 32 < K) GISSUE(cur ^ 1, k0 + 32);
        f16x8 af[4], bf[4];
#pragma unroll
        for (int i = 0; i < 4; i++) {
            af[i] = *(const f16x8*)&As[cur][wm + i * 16 + ln][(g ^ sw) * 8];
            bf[i] = *(const f16x8*)&Bs[cur][wn + i * 16 + ln][(g ^ sw) * 8];
        }
#pragma unroll
        for (int mt = 0; mt < 4; mt++)
#pragma unroll
            for (int nt = 0; nt < 4; nt++)
                acc[mt][nt] = MFMA16(af[mt], bf[nt], acc[mt][nt]);
        __syncthreads();  // drains next-tile staging; all waves done reading cur
        cur ^= 1;
    }
#undef GISSUE

    int rg = g * 4;
#pragma unroll
    for (int mt = 0; mt < 4; mt++)
#pragma unroll
        for (int nt = 0; nt < 4; nt++)
#pragma unroll
            for (int r = 0; r < 4; r++) {
                int row = m0 + wm + mt * 16 + rg + r;
                int col = n0 + wn + nt * 16 + ln;
                float v = acc[mt][nt][r];
                if (OUT_F16)
                    ((f16*)Cv)[(size_t)row * N + col] = (f16)v;
                else
                    ((float*)Cv)[(size_t)row * N + col] = v;
            }
}

// ---------------- flash attention v9: async-LDS staging, in-register P, split-k --------
// (verified round 6 -- unchanged)
__global__ __launch_bounds__(256, 2) void k_attn(const f16* __restrict__ QKV,
                                                 const f16* __restrict__ Vt,
                                                 f16* __restrict__ Opart,
                                                 float* __restrict__ Rsum) {
    __shared__ f16 Ks[2][64][64];
    __shared__ f16 Vs[2][64][64];  // V^T tile: [d][k]
    int bh = blockIdx.x, pi = blockIdx.y;  // pi 0..15
    int b = bh >> 4, h = bh & 15;
    int t = threadIdx.x, lane = t & 63, wq = t >> 6;
    int ln = lane & 15, g = lane >> 4, g8 = g * 8, rg = g * 4;
    int sx = ln & 7;  // read-side chunk xor

    int r0 = wq * 8 + (lane >> 3);        // phys row for instr 0 (0..31)
    int cp = lane & 7;
    int cl = (cp ^ (r0 & 7)) * 8;         // logical col (f16 elems) to fetch
    int gk0 = ((r0 & 16) >> 2) | ((r0 & 12) << 1) | (r0 & 3);  // glob(r0)
    const f16* Kb = QKV + (size_t)b * 2048 * 3072 + 1024 + h * 64;
    const f16* Vb = Vt + (size_t)bh * 64 * 2048;
    const f16* gK0 = Kb + (size_t)gk0 * 3072 + cl;
    const f16* gK1 = Kb + (size_t)(gk0 + 32) * 3072 + cl;
    const f16* gV0 = Vb + (size_t)r0 * 2048 + cl;
    const f16* gV1 = Vb + (size_t)(r0 + 32) * 2048 + cl;

    const float C_SCL = 0.18033688f;   // 0.125 * log2(e)
    const float C_MSK = -72.134752f;   // -50 * log2(e)
    f16x8 ones;
#pragma unroll
    for (int j = 0; j < 8; j++) ones[j] = (f16)1.f;

    int nk0 = 16 - pi;  // phase-0 tile count; total tiles always 17

#define ISSUE(bi, j)                                                      \
    do {                                                                  \
        int jj = (j);                                                     \
        int kt_ = (jj < nk0) ? jj : jj - nk0 + pi + 1;                    \
        size_t kO = (size_t)kt_ * 64;                                     \
        async16(&Ks[bi][wq * 8][0],      gK0 + kO * 3072);                \
        async16(&Ks[bi][32 + wq * 8][0], gK1 + kO * 3072);                \
        async16(&Vs[bi][wq * 8][0],      gV0 + kO);                       \
        async16(&Vs[bi][32 + wq * 8][0], gV1 + kO);                       \
    } while (0)

    ISSUE(0, 0);
    __syncthreads();  // barrier drains vmcnt -> tile 0 staged

    int i = 0;
    for (int phase = 0; phase < 2; phase++) {
        int qt  = phase ? pi : 15 - pi;
        int ktB = phase ? pi + 1 : 0;
        int ktE = phase ? 2 * pi + 2 : 16 - pi;
        int q0 = qt * 128;

        f16x8 bq[2][2];
#pragma unroll
        for (int nt = 0; nt < 2; nt++)
#pragma unroll
            for (int kd = 0; kd < 2; kd++)
                bq[nt][kd] = *(const f16x8*)(QKV +
                    (size_t)(b * 2048 + q0 + wq * 32 + nt * 16 + ln) * 3072 +
                    h * 64 + kd * 32 + g8);

        f32x4 oacc[2][4] = {};
        f32x4 osum[2] = {};

        for (int kt = ktB; kt < ktE; kt++, i++) {
            int cur = i & 1;
            int k0 = kt * 64;
            bool active = (k0 <= q0 + wq * 32 + 31);  // wave-uniform

            if (i + 1 < 17) ISSUE(cur ^ 1, i + 1);

            if (active) {
                f16x8 ak[2][4];
#pragma unroll
                for (int kd = 0; kd < 2; kd++)
#pragma unroll
                    for (int mt = 0; mt < 4; mt++)
                        ak[kd][mt] = *(const f16x8*)
                            &Ks[cur][mt * 16 + ln][((kd * 4 + g) ^ sx) * 8];
                f32x4 sacc[4][2] = {};
#pragma unroll
                for (int kd = 0; kd < 2; kd++)
#pragma unroll
                    for (int mt = 0; mt < 4; mt++)
#pragma unroll
                        for (int nt = 0; nt < 2; nt++)
                            sacc[mt][nt] = MFMA16(ak[kd][mt], bq[nt][kd], sacc[mt][nt]);

                bool needs_mask = (k0 + 63 > q0 + wq * 32);
                f16x8 ap[2][2];
#pragma unroll
                for (int nt = 0; nt < 2; nt++) {
                    int q = q0 + wq * 32 + nt * 16 + ln;
#pragma unroll
                    for (int mt = 0; mt < 4; mt++) {
                        int kb = mt >> 1, hi4 = (mt & 1) * 4;
#pragma unroll
                        for (int r = 0; r < 4; r++) {
                            float e;
                            if (needs_mask) {
                                int kk = k0 + kb * 32 + hi4 + 8 * g + r;
                                e = __builtin_amdgcn_exp2f(
                                    fmaf(sacc[mt][nt][r], C_SCL, (kk > q) ? C_MSK : 0.f));
                            } else {
                                e = __builtin_amdgcn_exp2f(sacc[mt][nt][r] * C_SCL);
                            }
                            ap[nt][kb][hi4 + r] = (f16)e;
                        }
                    }
                }

#pragma unroll
                for (int kk = 0; kk < 2; kk++) {
                    f16x8 bv[4];
#pragma unroll
                    for (int dt = 0; dt < 4; dt++)
                        bv[dt] = *(const f16x8*)
                            &Vs[cur][dt * 16 + ln][((kk * 4 + g) ^ sx) * 8];
#pragma unroll
                    for (int nt = 0; nt < 2; nt++) {
#pragma unroll
                        for (int dt = 0; dt < 4; dt++)
                            oacc[nt][dt] = MFMA16(ap[nt][kk], bv[dt], oacc[nt][dt]);
                        osum[nt] = MFMA16(ap[nt][kk], ones, osum[nt]);
                    }
                }
            }
            __syncthreads();  // drains tile i+1 staging; all waves done reading cur
        }

        int u = (bh * 16 + qt) * 2 + phase;
#pragma unroll
        for (int nt = 0; nt < 2; nt++)
#pragma unroll
            for (int r = 0; r < 4; r++) {
                float rs = osum[nt][r];
                float inv = __builtin_amdgcn_rcpf(fmaxf(rs, 1e-30f));
                int q = wq * 32 + nt * 16 + rg + r;
                if (ln == 0) Rsum[u * 128 + q] = rs;
#pragma unroll
                for (int dt = 0; dt < 4; dt++)
                    Opart[(size_t)u * 8192 + q * 64 + dt * 16 + ln] =
                        (f16)(oacc[nt][dt][r] * inv);
            }
    }
#undef ISSUE
}

// ---------------- merge split-k partials: O = (rs0*O0 + rs1*O1)/(rs0+rs1) ----------------
__global__ __launch_bounds__(256) void k_merge(const f16* __restrict__ Op,
                                               const float* __restrict__ Rs,
                                               f16* __restrict__ Ob) {
    int idx = blockIdx.x * 256 + threadIdx.x;  // 64bh*16qt*128q*8chunks = 1,048,576
    int d8 = idx & 7;
    int q  = (idx >> 3) & 127;
    int qt = (idx >> 10) & 15;
    int bh = idx >> 14;
    int b = bh >> 4, hd = bh & 15;
    int u0 = (bh * 16 + qt) * 2;
    float rs0 = Rs[u0 * 128 + q], rs1 = Rs[(u0 + 1) * 128 + q];
    float inv = __builtin_amdgcn_rcpf(rs0 + rs1);  // rs0 > 0 always (diagonal in half 0)
    f16x8 o0 = *(const f16x8*)(Op + (size_t)u0 * 8192 + q * 64 + d8 * 8);
    f16x8 o1 = *(const f16x8*)(Op + (size_t)(u0 + 1) * 8192 + q * 64 + d8 * 8);
    f16x8 o;
#pragma unroll
    for (int j = 0; j < 8; j++)
        o[j] = (f16)((rs0 * (float)o0[j] + rs1 * (float)o1[j]) * inv);
    *(f16x8*)(Ob + (size_t)(b * 2048 + qt * 128 + q) * 1024 + hd * 64 + d8 * 8) = o;
}

// ---------------- host launch ----------------
extern "C" void kernel_launch(void* const* d_in, const int* in_sizes, int n_in,
                              void* d_out, int out_size, void* d_ws, size_t ws_size,
                              hipStream_t stream) {
    const float* x = (const float*)d_in[0];
    const float* Wq = (const float*)d_in[1];
    const float* Wk = (const float*)d_in[2];
    const float* Wv = (const float*)d_in[3];
    const float* Wr = (const float*)d_in[4];
    float* out = (float*)d_out;

    f16* ws = (f16*)d_ws;
    f16* xb    = ws;                    // 8192*1024
    f16* Wqkvt = xb + 8388608;          // 3072*1024
    f16* Wrt   = Wqkvt + 3145728;       // 1024*1024
    f16* QKVb  = Wrt + 1048576;         // 8192*3072
    f16* Vtb   = QKVb + 25165824;       // 64bh * 64d * 2048s
    f16* Obuf  = Vtb + 8388608;         // 8192*1024
    f16* Opart = Obuf + 8388608;        // 2048 units * 128q * 64d
    float* Rsum = (float*)(Opart + 16777216);  // 2048 units * 128q

    k_prep<<<12288, 256, 0, stream>>>(x, Wq, Wk, Wv, Wr, xb, Wqkvt, Wrt);
    k_gemm_bt<true><<<dim3(24, 64), 256, 0, stream>>>(xb, Wqkvt, QKVb, 8192, 3072, 1024);
    dim3 tb(32, 8);
    k_transpose_v<<<dim3(64, 2, 64), tb, 0, stream>>>(QKVb, Vtb);
    k_attn<<<dim3(64, 16), 256, 0, stream>>>(QKVb, Vtb, Opart, Rsum);
    k_merge<<<4096, 256, 0, stream>>>(Opart, Rsum, Obuf);
    k_gemm_bt<false><<<dim3(8, 64), 256, 0, stream>>>(Obuf, Wrt, out, 8192, 1024, 1024);
}

// Round 8
// 270.231 us; speedup vs baseline: 2.0360x; 1.0084x over previous
//
#include <hip/hip_runtime.h>

typedef _Float16 f16;
typedef _Float16 f16x8 __attribute__((ext_vector_type(8)));
typedef _Float16 f16x4 __attribute__((ext_vector_type(4)));
typedef float f32x4 __attribute__((ext_vector_type(4)));

#define MFMA16(A, B, C) __builtin_amdgcn_mfma_f32_16x16x32_f16((A), (B), (C), 0, 0, 0)

// async global->LDS, 16B per lane, dest = wave-uniform base + lane*16
__device__ __forceinline__ void async16(void* lds, const void* gp) {
    __builtin_amdgcn_global_load_lds(
        (__attribute__((address_space(1))) void*)(gp),
        (__attribute__((address_space(3))) void*)(lds), 16, 0, 0);
}

// ---------------- fused prep: fp32->fp16 cast of x  +  transpose-cast of 4 weights -----
__global__ __launch_bounds__(256) void k_prep(const float* __restrict__ x,
                                              const float* __restrict__ Wq,
                                              const float* __restrict__ Wk,
                                              const float* __restrict__ Wv,
                                              const float* __restrict__ Wr,
                                              f16* __restrict__ xb,
                                              f16* __restrict__ Wqkvt,
                                              f16* __restrict__ Wrt) {
    __shared__ float tile[32][33];
    int bid = blockIdx.x;
    if (bid < 8192) {
        int i = (bid * 256 + threadIdx.x) * 4;  // 8192*256*4 = 8388608 exactly
        float4 v = *(const float4*)(x + i);
        f16x4 o = {(f16)v.x, (f16)v.y, (f16)v.z, (f16)v.w};
        *(f16x4*)(xb + i) = o;
    } else {
        int wid = bid - 8192;  // [0,4096)
        int z = wid >> 10;
        int tid = wid & 1023;
        const float* W = (z == 0) ? Wq : (z == 1) ? Wk : (z == 2) ? Wv : Wr;
        f16* Wt = (z == 3) ? Wrt : Wqkvt + z * 1048576;
        int c0 = (tid & 31) * 32, r0 = (tid >> 5) * 32;
        int tx = threadIdx.x & 31, ty = threadIdx.x >> 5;  // 32 x 8
#pragma unroll
        for (int j = 0; j < 32; j += 8)
            tile[ty + j][tx] = W[(r0 + ty + j) * 1024 + c0 + tx];
        __syncthreads();
#pragma unroll
        for (int j = 0; j < 32; j += 8)
            Wt[(c0 + ty + j) * 1024 + r0 + tx] = (f16)tile[tx][ty + j];
    }
}

// ---------------- transpose V slice of QKV into Vt[bh][d][s] ----------------
__global__ __launch_bounds__(256) void k_transpose_v(const f16* __restrict__ QKV,
                                                     f16* __restrict__ Vt) {
    __shared__ f16 tile[32][33];
    int s0 = blockIdx.x * 32;
    int d0 = blockIdx.y * 32;
    int bh = blockIdx.z;
    int b = bh >> 4, h = bh & 15;
    int tx = threadIdx.x, ty = threadIdx.y;  // 32 x 8
#pragma unroll
    for (int j = 0; j < 32; j += 8)
        tile[ty + j][tx] = QKV[(b * 2048 + s0 + ty + j) * 3072 + 2048 + h * 64 + d0 + tx];
    __syncthreads();
#pragma unroll
    for (int j = 0; j < 32; j += 8)
        Vt[(bh * 64 + d0 + ty + j) * 2048 + s0 + tx] = tile[tx][ty + j];
}

// ---------------- GEMM v3: 128x128 tile, BK=32, 3-buffer 2-deep counted-vmcnt pipeline --
// T4 (counted vmcnt): 2 tiles in flight; per K-step wait vmcnt(4) -- only tile i's 4
// loads -- so tile i+1's loads stay in flight ACROSS the barrier (never drain to 0 in
// the loop; AITER pattern). Raw s_barrier (not __syncthreads) so the compiler doesn't
// re-insert a vmcnt(0) drain. Hazard ledger:
//   RAW: each wave's vmcnt(4)+lgkmcnt(0) guarantees its own tile-i stores landed and its
//        ds_reads fully executed; s_barrier publishes cross-wave. Last iter: vmcnt(0).
//   WAR: buf (i+2)%3 was last read as tile i-1, complete before the PREVIOUS barrier.
// sched_barrier(0) after the barrier pins ds_reads below it (rule 18).
// Fragment/staging maps identical to the round-6/7 verified kernel.
template <bool OUT_F16>
__global__ __launch_bounds__(256) void k_gemm_bt(const f16* __restrict__ A,
                                                 const f16* __restrict__ Bt,
                                                 void* __restrict__ Cv,
                                                 int M, int N, int K) {
    __shared__ f16 As[3][128][32];
    __shared__ f16 Bs[3][128][32];
    int t = threadIdx.x;
    int lane = t & 63, w = t >> 6;
    int wm = (w >> 1) * 64, wn = (w & 1) * 64;
    int m0 = blockIdx.y * 128, n0 = blockIdx.x * 128;
    int ln = lane & 15, g = lane >> 4;

    // async staging map: two 64-chunk instructions per matrix per wave
    int lin0 = w * 128 + lane, lin1 = lin0 + 64;
    int r0 = lin0 >> 2, c0 = (lin0 & 3) ^ ((r0 >> 1) & 3);
    int r1 = lin1 >> 2, c1 = (lin1 & 3) ^ ((r1 >> 1) & 3);
    const f16* gA0 = A + (size_t)(m0 + r0) * K + c0 * 8;
    const f16* gA1 = A + (size_t)(m0 + r1) * K + c1 * 8;
    const f16* gB0 = Bt + (size_t)(n0 + r0) * K + c0 * 8;
    const f16* gB1 = Bt + (size_t)(n0 + r1) * K + c1 * 8;

    f32x4 acc[4][4] = {};
    int sw = (ln >> 1) & 3;

#define GISSUE(bi, kk)                                    \
    do {                                                  \
        f16* lA = &As[0][0][0] + (bi) * 4096 + w * 1024;  \
        f16* lB = &Bs[0][0][0] + (bi) * 4096 + w * 1024;  \
        async16(lA, gA0 + (kk));                          \
        async16(lA + 512, gA1 + (kk));                    \
        async16(lB, gB0 + (kk));                          \
        async16(lB + 512, gB1 + (kk));                    \
    } while (0)

    GISSUE(0, 0);
    GISSUE(1, 32);

    int b0 = 0, b1 = 1, b2 = 2;
    for (int k0 = 0; k0 < K; k0 += 32) {
        if (k0 + 32 < K)
            asm volatile("s_waitcnt vmcnt(4) lgkmcnt(0)" ::: "memory");
        else
            asm volatile("s_waitcnt vmcnt(0) lgkmcnt(0)" ::: "memory");
        __builtin_amdgcn_s_barrier();
        __builtin_amdgcn_sched_barrier(0);
        if (k0 + 64 < K) GISSUE(b2, k0 + 64);

        f16x8 af[4], bf[4];
#pragma unroll
        for (int i = 0; i < 4; i++) {
            af[i] = *(const f16x8*)&As[b0][wm + i * 16 + ln][(g ^ sw) * 8];
            bf[i] = *(const f16x8*)&Bs[b0][wn + i * 16 + ln][(g ^ sw) * 8];
        }
#pragma unroll
        for (int mt = 0; mt < 4; mt++)
#pragma unroll
            for (int nt = 0; nt < 4; nt++)
                acc[mt][nt] = MFMA16(af[mt], bf[nt], acc[mt][nt]);

        int tmp = b0; b0 = b1; b1 = b2; b2 = tmp;
    }
#undef GISSUE

    int rg = g * 4;
#pragma unroll
    for (int mt = 0; mt < 4; mt++)
#pragma unroll
        for (int nt = 0; nt < 4; nt++)
#pragma unroll
            for (int r = 0; r < 4; r++) {
                int row = m0 + wm + mt * 16 + rg + r;
                int col = n0 + wn + nt * 16 + ln;
                float v = acc[mt][nt][r];
                if (OUT_F16)
                    ((f16*)Cv)[(size_t)row * N + col] = (f16)v;
                else
                    ((float*)Cv)[(size_t)row * N + col] = v;
            }
}

// ---------------- flash attention v9: async-LDS staging, in-register P, split-k --------
// (verified rounds 6-7 -- unchanged)
__global__ __launch_bounds__(256, 2) void k_attn(const f16* __restrict__ QKV,
                                                 const f16* __restrict__ Vt,
                                                 f16* __restrict__ Opart,
                                                 float* __restrict__ Rsum) {
    __shared__ f16 Ks[2][64][64];
    __shared__ f16 Vs[2][64][64];  // V^T tile: [d][k]
    int bh = blockIdx.x, pi = blockIdx.y;  // pi 0..15
    int b = bh >> 4, h = bh & 15;
    int t = threadIdx.x, lane = t & 63, wq = t >> 6;
    int ln = lane & 15, g = lane >> 4, g8 = g * 8, rg = g * 4;
    int sx = ln & 7;  // read-side chunk xor

    int r0 = wq * 8 + (lane >> 3);        // phys row for instr 0 (0..31)
    int cp = lane & 7;
    int cl = (cp ^ (r0 & 7)) * 8;         // logical col (f16 elems) to fetch
    int gk0 = ((r0 & 16) >> 2) | ((r0 & 12) << 1) | (r0 & 3);  // glob(r0)
    const f16* Kb = QKV + (size_t)b * 2048 * 3072 + 1024 + h * 64;
    const f16* Vb = Vt + (size_t)bh * 64 * 2048;
    const f16* gK0 = Kb + (size_t)gk0 * 3072 + cl;
    const f16* gK1 = Kb + (size_t)(gk0 + 32) * 3072 + cl;
    const f16* gV0 = Vb + (size_t)r0 * 2048 + cl;
    const f16* gV1 = Vb + (size_t)(r0 + 32) * 2048 + cl;

    const float C_SCL = 0.18033688f;   // 0.125 * log2(e)
    const float C_MSK = -72.134752f;   // -50 * log2(e)
    f16x8 ones;
#pragma unroll
    for (int j = 0; j < 8; j++) ones[j] = (f16)1.f;

    int nk0 = 16 - pi;  // phase-0 tile count; total tiles always 17

#define ISSUE(bi, j)                                                      \
    do {                                                                  \
        int jj = (j);                                                     \
        int kt_ = (jj < nk0) ? jj : jj - nk0 + pi + 1;                    \
        size_t kO = (size_t)kt_ * 64;                                     \
        async16(&Ks[bi][wq * 8][0],      gK0 + kO * 3072);                \
        async16(&Ks[bi][32 + wq * 8][0], gK1 + kO * 3072);                \
        async16(&Vs[bi][wq * 8][0],      gV0 + kO);                       \
        async16(&Vs[bi][32 + wq * 8][0], gV1 + kO);                       \
    } while (0)

    ISSUE(0, 0);
    __syncthreads();  // barrier drains vmcnt -> tile 0 staged

    int i = 0;
    for (int phase = 0; phase < 2; phase++) {
        int qt  = phase ? pi : 15 - pi;
        int ktB = phase ? pi + 1 : 0;
        int ktE = phase ? 2 * pi + 2 : 16 - pi;
        int q0 = qt * 128;

        f16x8 bq[2][2];
#pragma unroll
        for (int nt = 0; nt < 2; nt++)
#pragma unroll
            for (int kd = 0; kd < 2; kd++)
                bq[nt][kd] = *(const f16x8*)(QKV +
                    (size_t)(b * 2048 + q0 + wq * 32 + nt * 16 + ln) * 3072 +
                    h * 64 + kd * 32 + g8);

        f32x4 oacc[2][4] = {};
        f32x4 osum[2] = {};

        for (int kt = ktB; kt < ktE; kt++, i++) {
            int cur = i & 1;
            int k0 = kt * 64;
            bool active = (k0 <= q0 + wq * 32 + 31);  // wave-uniform

            if (i + 1 < 17) ISSUE(cur ^ 1, i + 1);

            if (active) {
                f16x8 ak[2][4];
#pragma unroll
                for (int kd = 0; kd < 2; kd++)
#pragma unroll
                    for (int mt = 0; mt < 4; mt++)
                        ak[kd][mt] = *(const f16x8*)
                            &Ks[cur][mt * 16 + ln][((kd * 4 + g) ^ sx) * 8];
                f32x4 sacc[4][2] = {};
#pragma unroll
                for (int kd = 0; kd < 2; kd++)
#pragma unroll
                    for (int mt = 0; mt < 4; mt++)
#pragma unroll
                        for (int nt = 0; nt < 2; nt++)
                            sacc[mt][nt] = MFMA16(ak[kd][mt], bq[nt][kd], sacc[mt][nt]);

                bool needs_mask = (k0 + 63 > q0 + wq * 32);
                f16x8 ap[2][2];
#pragma unroll
                for (int nt = 0; nt < 2; nt++) {
                    int q = q0 + wq * 32 + nt * 16 + ln;
#pragma unroll
                    for (int mt = 0; mt < 4; mt++) {
                        int kb = mt >> 1, hi4 = (mt & 1) * 4;
#pragma unroll
                        for (int r = 0; r < 4; r++) {
                            float e;
                            if (needs_mask) {
                                int kk = k0 + kb * 32 + hi4 + 8 * g + r;
                                e = __builtin_amdgcn_exp2f(
                                    fmaf(sacc[mt][nt][r], C_SCL, (kk > q) ? C_MSK : 0.f));
                            } else {
                                e = __builtin_amdgcn_exp2f(sacc[mt][nt][r] * C_SCL);
                            }
                            ap[nt][kb][hi4 + r] = (f16)e;
                        }
                    }
                }

#pragma unroll
                for (int kk = 0; kk < 2; kk++) {
                    f16x8 bv[4];
#pragma unroll
                    for (int dt = 0; dt < 4; dt++)
                        bv[dt] = *(const f16x8*)
                            &Vs[cur][dt * 16 + ln][((kk * 4 + g) ^ sx) * 8];
#pragma unroll
                    for (int nt = 0; nt < 2; nt++) {
#pragma unroll
                        for (int dt = 0; dt < 4; dt++)
                            oacc[nt][dt] = MFMA16(ap[nt][kk], bv[dt], oacc[nt][dt]);
                        osum[nt] = MFMA16(ap[nt][kk], ones, osum[nt]);
                    }
                }
            }
            __syncthreads();  // drains tile i+1 staging; all waves done reading cur
        }

        int u = (bh * 16 + qt) * 2 + phase;
#pragma unroll
        for (int nt = 0; nt < 2; nt++)
#pragma unroll
            for (int r = 0; r < 4; r++) {
                float rs = osum[nt][r];
                float inv = __builtin_amdgcn_rcpf(fmaxf(rs, 1e-30f));
                int q = wq * 32 + nt * 16 + rg + r;
                if (ln == 0) Rsum[u * 128 + q] = rs;
#pragma unroll
                for (int dt = 0; dt < 4; dt++)
                    Opart[(size_t)u * 8192 + q * 64 + dt * 16 + ln] =
                        (f16)(oacc[nt][dt][r] * inv);
            }
    }
#undef ISSUE
}

// ---------------- merge split-k partials: O = (rs0*O0 + rs1*O1)/(rs0+rs1) ----------------
__global__ __launch_bounds__(256) void k_merge(const f16* __restrict__ Op,
                                               const float* __restrict__ Rs,
                                               f16* __restrict__ Ob) {
    int idx = blockIdx.x * 256 + threadIdx.x;  // 64bh*16qt*128q*8chunks = 1,048,576
    int d8 = idx & 7;
    int q  = (idx >> 3) & 127;
    int qt = (idx >> 10) & 15;
    int bh = idx >> 14;
    int b = bh >> 4, hd = bh & 15;
    int u0 = (bh * 16 + qt) * 2;
    float rs0 = Rs[u0 * 128 + q], rs1 = Rs[(u0 + 1) * 128 + q];
    float inv = __builtin_amdgcn_rcpf(rs0 + rs1);  // rs0 > 0 always (diagonal in half 0)
    f16x8 o0 = *(const f16x8*)(Op + (size_t)u0 * 8192 + q * 64 + d8 * 8);
    f16x8 o1 = *(const f16x8*)(Op + (size_t)(u0 + 1) * 8192 + q * 64 + d8 * 8);
    f16x8 o;
#pragma unroll
    for (int j = 0; j < 8; j++)
        o[j] = (f16)((rs0 * (float)o0[j] + rs1 * (float)o1[j]) * inv);
    *(f16x8*)(Ob + (size_t)(b * 2048 + qt * 128 + q) * 1024 + hd * 64 + d8 * 8) = o;
}

// ---------------- host launch ----------------
extern "C" void kernel_launch(void* const* d_in, const int* in_sizes, int n_in,
                              void* d_out, int out_size, void* d_ws, size_t ws_size,
                              hipStream_t stream) {
    const float* x = (const float*)d_in[0];
    const float* Wq = (const float*)d_in[1];
    const float* Wk = (const float*)d_in[2];
    const float* Wv = (const float*)d_in[3];
    const float* Wr = (const float*)d_in[4];
    float* out = (float*)d_out;

    f16* ws = (f16*)d_ws;
    f16* xb    = ws;                    // 8192*1024
    f16* Wqkvt = xb + 8388608;          // 3072*1024
    f16* Wrt   = Wqkvt + 3145728;       // 1024*1024
    f16* QKVb  = Wrt + 1048576;         // 8192*3072
    f16* Vtb   = QKVb + 25165824;       // 64bh * 64d * 2048s
    f16* Obuf  = Vtb + 8388608;         // 8192*1024
    f16* Opart = Obuf + 8388608;        // 2048 units * 128q * 64d
    float* Rsum = (float*)(Opart + 16777216);  // 2048 units * 128q

    k_prep<<<12288, 256, 0, stream>>>(x, Wq, Wk, Wv, Wr, xb, Wqkvt, Wrt);
    k_gemm_bt<true><<<dim3(24, 64), 256, 0, stream>>>(xb, Wqkvt, QKVb, 8192, 3072, 1024);
    dim3 tb(32, 8);
    k_transpose_v<<<dim3(64, 2, 64), tb, 0, stream>>>(QKVb, Vtb);
    k_attn<<<dim3(64, 16), 256, 0, stream>>>(QKVb, Vtb, Opart, Rsum);
    k_merge<<<4096, 256, 0, stream>>>(Opart, Rsum, Obuf);
    k_gemm_bt<false><<<dim3(8, 64), 256, 0, stream>>>(Obuf, Wrt, out, 8192, 1024, 1024);
}